// Round 13
// baseline (993.921 us; speedup 1.0000x reference)
//
#include <hip/hip_runtime.h>

#define HH 180
#define WW 180
#define HWN 32400
#define CC 128
#define CINN 384
#define KK 10
#define PP 200
#define NHH 8
#define BB 2
#define NTOT 324000  // K*H*W per batch
#define TKBINS (1 << 18)
#define KSPLIT 16

typedef _Float16 half8 __attribute__((ext_vector_type(8)));
typedef _Float16 half4 __attribute__((ext_vector_type(4)));
typedef float f32x16 __attribute__((ext_vector_type(16)));
typedef unsigned int u32;

static __device__ __forceinline__ f32x16 MFMA16(half8 a, half8 b, f32x16 c) {
    return __builtin_amdgcn_mfma_f32_32x32x16_f16(a, b, c, 0, 0, 0);
}
static __device__ __forceinline__ half8 mkh8(u32 a, u32 b, u32 c, u32 d) {
    union { u32 u[4]; half8 h; } x; x.u[0] = a; x.u[1] = b; x.u[2] = c; x.u[3] = d; return x.h;
}
static __device__ __forceinline__ u32 pkh(float a, float b) {
    union { _Float16 h[2]; u32 u; } x; x.h[0] = (_Float16)a; x.h[1] = (_Float16)b; return x.u;
}

// ------ weight split image: [bidx=ch*9+tap][t2][q4][cout128][8 halves] --------
__global__ void k_wsplit(const float* __restrict__ w, _Float16* __restrict__ img, int cint) {
    const int e = blockIdx.x * 256 + threadIdx.x;
    const int total = (cint / 32) * 9 * 8192;
    if (e >= total) return;
    const int ii = e & 7, cout = (e >> 3) & 127, q = (e >> 10) & 3, t = (e >> 12) & 1;
    const int bidx = e >> 13, tap = bidx % 9, ch = bidx / 9;
    const int cin = ch * 32 + q * 8 + ii;
    const float v = w[((size_t)cout * cint + cin) * 9 + tap];
    const _Float16 h = (_Float16)v;
    img[e] = (t == 0) ? h : (_Float16)((v - (float)h) * 256.f);
}

// ------ hm2 weight split image: [bidx][t2][q4][cout32(10 real)][8 halves] -----
__global__ void k_wsplit_hm(const float* __restrict__ w, _Float16* __restrict__ img) {
    const int e = blockIdx.x * 256 + threadIdx.x;
    const int total = 4 * 9 * 2048;
    if (e >= total) return;
    const int ii = e & 7, co = (e >> 3) & 31, q = (e >> 8) & 3, t = (e >> 10) & 1;
    const int bidx = e >> 11, tap = bidx % 9, ch = bidx / 9;
    const int cin = ch * 32 + q * 8 + ii;
    const float v = (co < 10) ? w[((size_t)co * 128 + cin) * 9 + tap] : 0.f;
    const _Float16 h = (_Float16)v;
    img[e] = (t == 0) ? h : (_Float16)((v - (float)h) * 256.f);
}

// ------ x transpose+split: x[b][cin][y][x] -> xs[b][y][ch][t][x][cin32] -------
__global__ __launch_bounds__(256) void k_xsplit(const float* __restrict__ x,
    _Float16* __restrict__ out, int CIN, int NCH)
{
    __shared__ float tile[32][184];
    const int ch = blockIdx.x, y = blockIdx.y, b = blockIdx.z;
    const int tid = threadIdx.x;
    for (int s = tid; s < 32 * 180; s += 256) {
        const int c = s / 180, px = s % 180;
        tile[c][px] = x[(((size_t)b * CIN + ch * 32 + c) * HH + y) * WW + px];
    }
    __syncthreads();
    const size_t pbase = ((((size_t)b * 180 + y) * NCH + ch) * 2) * (180 * 32);
    for (int tt = tid; tt < 1440; tt += 256) {
        const int t = tt / 720, u = tt % 720, px = u >> 2, q = u & 3;
        half8 hv;
#pragma unroll
        for (int j = 0; j < 8; ++j) {
            const float v = tile[q * 8 + j][px];
            const _Float16 h = (_Float16)v;
            hv[j] = (t == 0) ? h : (_Float16)((v - (float)h) * 256.f);
        }
        *(half8*)(out + pbase + (size_t)t * (180 * 32) + px * 32 + q * 8) = hv;
    }
}

// ------ MFMA 3x3 conv: cout-split blocks, direct-from-L2 W with 1-tap prefetch
// grid (6, 90, 2): x = xtile*2 + ch2 (ch2 fastest -> twin blocks L2-adjacent).
template<int NCH, int EPI, int WRITEF, int SPLIT>
__global__ __launch_bounds__(256, 3) void k_conv(
    const _Float16* __restrict__ xs, const _Float16* __restrict__ wimg,
    const float* __restrict__ bias, const float* __restrict__ g,
    const float* __restrict__ beta, float* __restrict__ outf,
    _Float16* __restrict__ outs)
{
    __shared__ __align__(16) char sh[36992];   // A 33792 | C epilogue 36864
    const int tid = threadIdx.x;
    const int b = blockIdx.z, ch2 = blockIdx.x & 1;
    const int oy0 = blockIdx.y * 2, ox0 = (blockIdx.x >> 1) * 64;
    const int wave = tid >> 6, l = tid & 63;
    const int wr = wave >> 1, nh = wave & 1;
    const int l31 = l & 31, kb = l >> 5;

    f32x16 acc1[2] = {};
    f32x16 acc2[2] = {};

    int wofs[2][2];
#pragma unroll
    for (int t = 0; t < 2; ++t)
#pragma unroll
        for (int s = 0; s < 2; ++s)
            wofs[t][s] = (((t * 4) + (s * 2 + kb)) * 128 + ch2 * 64 + nh * 32 + l31) * 16;

    half8 bwC[2][2], bwN[2][2];
#pragma unroll
    for (int t = 0; t < 2; ++t)
#pragma unroll
        for (int s = 0; s < 2; ++s)
            bwC[t][s] = *(const half8*)((const char*)wimg + wofs[t][s]);

#pragma unroll 1
    for (int ch = 0; ch < NCH; ++ch) {
        if (ch) __syncthreads();
#pragma unroll
        for (int k = 0; k < 9; ++k) {
            const int tt = tid + k * 256;
            if (tt < 2112) {
                const int seg = tt / 264, u = tt - seg * 264;
                const int t = seg >> 2, r = seg & 3;
                const int i = u >> 2, q = u & 3;
                const int gy = oy0 - 1 + r, gx = ox0 - 1 + i;
                uint4 v = {0u, 0u, 0u, 0u};
                if ((unsigned)gy < 180u && (unsigned)gx < 180u)
                    v = *(const uint4*)((const char*)xs +
                        (((((size_t)b * 180 + gy) * NCH + ch) * 2 + t) * 180 + gx) * 64 + q * 16);
                *(uint4*)(sh + ((t * 4 + r) * 4 + q) * 1056 + i * 16) = v;
            }
        }
        __syncthreads();
#pragma unroll
        for (int tap = 0; tap < 9; ++tap) {
            const int bidx = ch * 9 + tap;
            const bool pf = (bidx + 1 < NCH * 9);
            if (pf) {
                const char* wn = (const char*)wimg + (size_t)(bidx + 1) * 16384;
#pragma unroll
                for (int t = 0; t < 2; ++t)
#pragma unroll
                    for (int s = 0; s < 2; ++s)
                        bwN[t][s] = *(const half8*)(wn + wofs[t][s]);
            }
            const int ky = tap / 3, kx = tap % 3;
            const int rr = wr + ky;
#pragma unroll
            for (int s = 0; s < 2; ++s) {
                const int q = s * 2 + kb;
                half8 ah[2], al[2];
#pragma unroll
                for (int mf = 0; mf < 2; ++mf) {
                    const int io = (mf * 32 + l31 + kx) * 16;
                    ah[mf] = *(const half8*)(sh + ((rr) * 4 + q) * 1056 + io);
                    al[mf] = *(const half8*)(sh + ((4 + rr) * 4 + q) * 1056 + io);
                }
#pragma unroll
                for (int mf = 0; mf < 2; ++mf) {
                    acc1[mf] = MFMA16(ah[mf], bwC[0][s], acc1[mf]);
                    acc2[mf] = MFMA16(ah[mf], bwC[1][s], acc2[mf]);
                    acc2[mf] = MFMA16(al[mf], bwC[0][s], acc2[mf]);
                }
            }
            if (pf) {
#pragma unroll
                for (int t = 0; t < 2; ++t)
#pragma unroll
                    for (int s = 0; s < 2; ++s)
                        bwC[t][s] = bwN[t][s];
            }
        }
    }

    // epilogue: single phase through C [64co][2r][72pad] (reuses sh)
    float* C = (float*)sh;
    const float inv256 = 1.f / 256.f;
    __syncthreads();
#pragma unroll
    for (int mf = 0; mf < 2; ++mf)
#pragma unroll
        for (int reg = 0; reg < 16; ++reg) {
            const int px = mf * 32 + (reg & 3) + 8 * (reg >> 2) + 4 * kb;
            const int co = nh * 32 + l31;
            C[(co * 2 + wr) * 72 + px] = acc1[mf][reg] + acc2[mf][reg] * inv256;
        }
    __syncthreads();
    if (WRITEF) {
        for (int tt = tid; tt < 2048; tt += 256) {
            const int co = tt >> 5, rem = tt & 31, r = rem >> 4, qx = rem & 15;
            const int gx = ox0 + qx * 4;
            if (gx < WW) {
                float4 v = *(const float4*)&C[(co * 2 + r) * 72 + qx * 4];
                const int cout = ch2 * 64 + co;
                const float bv = bias[cout];
                v.x += bv; v.y += bv; v.z += bv; v.w += bv;
                if (EPI) {
                    const float gg = g[cout], bb = beta[cout];
                    v.x = fmaxf(gg * v.x + bb, 0.f); v.y = fmaxf(gg * v.y + bb, 0.f);
                    v.z = fmaxf(gg * v.z + bb, 0.f); v.w = fmaxf(gg * v.w + bb, 0.f);
                }
                *(float4*)(outf + (((size_t)b * 128 + cout) * HH + oy0 + r) * WW + gx) = v;
            }
        }
    }
    if (SPLIT) {
        for (int tt = tid; tt < 1024; tt += 256) {
            const int q = tt & 3, px = (tt >> 2) & 63, c2 = (tt >> 8) & 1, r = tt >> 9;
            const int gx = ox0 + px;
            if (gx < WW) {
                const int chg = ch2 * 2 + c2;
                half8 hv, lv;
#pragma unroll
                for (int j = 0; j < 8; ++j) {
                    const int col = c2 * 32 + q * 8 + j;
                    const int cout = ch2 * 64 + col;
                    float v = C[(col * 2 + r) * 72 + px] + bias[cout];
                    if (EPI) v = fmaxf(g[cout] * v + beta[cout], 0.f);
                    const _Float16 h = (_Float16)v;
                    hv[j] = h;
                    lv[j] = (_Float16)((v - (float)h) * 256.f);
                }
                char* dst = (char*)outs +
                    ((((size_t)b * 180 + (oy0 + r)) * 4 + chg) * 2) * 11520 + gx * 64 + q * 16;
                *(half8*)dst = hv;
                *(half8*)(dst + 11520) = lv;
            }
        }
    }
}

// ------ heatmap conv2 (128->10) via MFMA split + sigmoid ----------------------
template<int NCH>
__global__ __launch_bounds__(256, 3) void k_convhm2m(
    const _Float16* __restrict__ xs, const _Float16* __restrict__ wimg,
    const float* __restrict__ bias, float* __restrict__ hm_raw)
{
    __shared__ __align__(16) char sh[36992];
    const int tid = threadIdx.x;
    const int b = blockIdx.z;
    const int oy0 = blockIdx.y * 2, ox0 = blockIdx.x * 64;
    const int wave = tid >> 6, l = tid & 63;
    const int wr = wave >> 1, dup = wave & 1;
    const int l31 = l & 31, kb = l >> 5;

    f32x16 acc1[2] = {};
    f32x16 acc2[2] = {};

    const int q = dup * 2 + kb;
    int wofs[2];
#pragma unroll
    for (int t = 0; t < 2; ++t)
        wofs[t] = ((t * 4 + q) * 32 + l31) * 16;

#pragma unroll 1
    for (int ch = 0; ch < NCH; ++ch) {
        if (ch) __syncthreads();
#pragma unroll
        for (int k = 0; k < 9; ++k) {
            const int tt = tid + k * 256;
            if (tt < 2112) {
                const int seg = tt / 264, u = tt - seg * 264;
                const int t = seg >> 2, r = seg & 3;
                const int i = u >> 2, qq = u & 3;
                const int gy = oy0 - 1 + r, gx = ox0 - 1 + i;
                uint4 v = {0u, 0u, 0u, 0u};
                if ((unsigned)gy < 180u && (unsigned)gx < 180u)
                    v = *(const uint4*)((const char*)xs +
                        (((((size_t)b * 180 + gy) * NCH + ch) * 2 + t) * 180 + gx) * 64 + qq * 16);
                *(uint4*)(sh + ((t * 4 + r) * 4 + qq) * 1056 + i * 16) = v;
            }
        }
        __syncthreads();
        const char* wb = (const char*)wimg + (size_t)ch * 9 * 4096;
#pragma unroll
        for (int tap = 0; tap < 9; ++tap) {
            const char* wt = wb + tap * 4096;
            const half8 bw0 = *(const half8*)(wt + wofs[0]);
            const half8 bw1 = *(const half8*)(wt + wofs[1]);
            const int ky = tap / 3, kx = tap % 3;
            const int rr = wr + ky;
#pragma unroll
            for (int mf = 0; mf < 2; ++mf) {
                const int io = (mf * 32 + l31 + kx) * 16;
                const half8 ah = *(const half8*)(sh + ((rr) * 4 + q) * 1056 + io);
                const half8 al = *(const half8*)(sh + ((4 + rr) * 4 + q) * 1056 + io);
                acc1[mf] = MFMA16(ah, bw0, acc1[mf]);
                acc2[mf] = MFMA16(ah, bw1, acc2[mf]);
                acc2[mf] = MFMA16(al, bw0, acc2[mf]);
            }
        }
    }

    // pair-reduce dup0+dup1 through LDS (C1 at 0, C2 at float-offset 4160)
    float* C = (float*)sh;
    __syncthreads();
    if (dup == 0) {
#pragma unroll
        for (int mf = 0; mf < 2; ++mf)
#pragma unroll
            for (int reg = 0; reg < 16; ++reg) {
                const int px = mf * 32 + (reg & 3) + 8 * (reg >> 2) + 4 * kb;
                C[(wr * 32 + l31) * 65 + px] = acc1[mf][reg];
                C[4160 + (wr * 32 + l31) * 65 + px] = acc2[mf][reg];
            }
    }
    __syncthreads();
    if (dup == 1 && l31 < 10) {
        const float inv256 = 1.f / 256.f;
        const float bv = bias[l31];
#pragma unroll
        for (int mf = 0; mf < 2; ++mf)
#pragma unroll
            for (int reg = 0; reg < 16; ++reg) {
                const int px = mf * 32 + (reg & 3) + 8 * (reg >> 2) + 4 * kb;
                const int gx = ox0 + px;
                if (gx < WW) {
                    const float z = (C[(wr * 32 + l31) * 65 + px] + acc1[mf][reg])
                                  + (C[4160 + (wr * 32 + l31) * 65 + px] + acc2[mf][reg]) * inv256
                                  + bv;
                    hm_raw[(((size_t)b * 10 + l31) * HH + oy0 + wr) * WW + gx] =
                        1.f / (1.f + expf(-z));
                }
            }
    }
}

// ---------------- 3x3 local-max NMS mask + fused histogram --------------------
__global__ void k_nms(const float* __restrict__ hm, float* __restrict__ out,
                      unsigned* __restrict__ hist) {
    int i = blockIdx.x * 256 + threadIdx.x;
    if (i >= BB * KK * HWN) return;
    int xx = i % WW, yy = (i / WW) % HH, ck = i / HWN;
    float v = hm[i], m = v;
    for (int dy = -1; dy <= 1; ++dy) {
        int ny = yy + dy;
        if ((unsigned)ny >= (unsigned)HH) continue;
        for (int dx = -1; dx <= 1; ++dx) {
            int nx = xx + dx;
            if ((unsigned)nx >= (unsigned)WW) continue;
            m = fmaxf(m, hm[(size_t)ck * HWN + ny * WW + nx]);
        }
    }
    const float mv = (v == m) ? v : 0.f;
    out[i] = mv;
    const unsigned key = __float_as_uint(mv);
    if (key != 0u)
        atomicAdd(&hist[(size_t)(i / NTOT) * TKBINS + (key >> 14)], 1u);
}

// ---------------- exact top-200: parallel pipeline ----------------------------
__global__ __launch_bounds__(1024) void k_tkzero(unsigned* __restrict__ hist,
                                                 unsigned* __restrict__ ccnt) {
    const int i = blockIdx.x * 1024 + threadIdx.x;
    hist[i] = 0u;
    if (i < 2) ccnt[i] = 0u;
}

__global__ __launch_bounds__(1024) void k_tkscan(const unsigned* __restrict__ hist,
                                                 unsigned* __restrict__ pivot) {
    __shared__ unsigned ls[1024];
    __shared__ unsigned s_owner, s_carry;
    const int b = blockIdx.x, t = threadIdx.x;
    const unsigned* h = hist + (size_t)b * TKBINS;
    if (t == 0) { s_owner = 0u; s_carry = 0u; pivot[b] = 0u; }
    unsigned s = 0;
    const int base = t * 256;
    for (int i = 0; i < 256; ++i) s += h[base + i];
    ls[t] = s;
    __syncthreads();
    for (int off = 1; off < 1024; off <<= 1) {
        const unsigned add = (t + off < 1024) ? ls[t + off] : 0u;
        __syncthreads();
        ls[t] += add;
        __syncthreads();
    }
    {
        const unsigned here = ls[t];
        const unsigned above = (t + 1 < 1024) ? ls[t + 1] : 0u;
        if (here >= 200u && above < 200u) { s_owner = (unsigned)t; s_carry = above; }
    }
    __syncthreads();
    const int owner = (int)s_owner;
    const unsigned carry = s_carry;
    __syncthreads();
    ls[t] = (t < 256) ? h[owner * 256 + t] : 0u;
    __syncthreads();
    for (int off = 1; off < 1024; off <<= 1) {
        const unsigned add = (t + off < 1024) ? ls[t + off] : 0u;
        __syncthreads();
        ls[t] += add;
        __syncthreads();
    }
    if (t < 256) {
        const unsigned here = carry + ls[t];
        const unsigned above = carry + ((t + 1 < 1024) ? ls[t + 1] : 0u);
        if (here >= 200u && above < 200u)
            pivot[b] = (unsigned)(owner * 256 + t) << 14;
    }
}

__global__ __launch_bounds__(1024) void k_tkcollect(const float* __restrict__ hm_msk,
    const unsigned* __restrict__ pivot, unsigned long long* __restrict__ cand,
    unsigned* __restrict__ ccnt) {
    const int b = blockIdx.y;
    const int i = blockIdx.x * 1024 + threadIdx.x;
    if (i >= NTOT) return;
    const unsigned key = __float_as_uint(hm_msk[(size_t)b * NTOT + i]);
    if (key >= pivot[b] && key != 0u) {
        const unsigned pos = atomicAdd(&ccnt[b], 1u);
        if (pos < 4096u)
            cand[(size_t)b * 4096 + pos] = (((unsigned long long)(~key)) << 32) | (unsigned)i;
    }
}

__global__ __launch_bounds__(1024) void k_tksort(const unsigned long long* __restrict__ cand,
    const unsigned* __restrict__ ccnt, int* __restrict__ top_idx) {
    __shared__ unsigned long long sb[4096];
    const int b = blockIdx.x, t = threadIdx.x;
    const unsigned cnt = ccnt[b] < 4096u ? ccnt[b] : 4096u;
    if (cnt <= 1024u) {
        sb[t] = ((unsigned)t < cnt) ? cand[(size_t)b * 4096 + t] : 0xFFFFFFFFFFFFFFFFull;
        __syncthreads();
        for (int k = 2; k <= 1024; k <<= 1) {
            for (int j = k >> 1; j > 0; j >>= 1) {
                const int ixj = t ^ j;
                if (ixj > t) {
                    const unsigned long long a = sb[t], c = sb[ixj];
                    const bool up = ((t & k) == 0);
                    if ((a > c) == up) { sb[t] = c; sb[ixj] = a; }
                }
                __syncthreads();
            }
        }
    } else {
        for (int e = t; e < 4096; e += 1024)
            sb[e] = ((unsigned)e < cnt) ? cand[(size_t)b * 4096 + e] : 0xFFFFFFFFFFFFFFFFull;
        __syncthreads();
        for (int k = 2; k <= 4096; k <<= 1) {
            for (int j = k >> 1; j > 0; j >>= 1) {
                for (int e = t; e < 4096; e += 1024) {
                    const int ixj = e ^ j;
                    if (ixj > e) {
                        const unsigned long long a = sb[e], c = sb[ixj];
                        const bool up = ((e & k) == 0);
                        if ((a > c) == up) { sb[e] = c; sb[ixj] = a; }
                    }
                }
                __syncthreads();
            }
        }
    }
    if (t < 200) top_idx[b * 200 + t] = (int)(sb[t] & 0xFFFFFFFFull) % HWN;
}

// ------ kpe for all BEV positions (24 pos/block, stored transposed) -----------
__global__ __launch_bounds__(128) void k_kpe(const float* __restrict__ w1,
    const float* __restrict__ b1, const float* __restrict__ w2,
    const float* __restrict__ b2, float* __restrict__ kpeT)
{
    __shared__ float pe[24][258];
    __shared__ float hid[24][130];
    const int tid = threadIdx.x;
    const int pos0 = blockIdx.x * 24;
    const int half = tid >> 6, m = tid & 63;
    const float dimt = 1.f + (float)m * 0.015625f;
#pragma unroll
    for (int p = 0; p < 24; ++p) {
        const int pos = pos0 + p;
        const int i = pos / WW, j = pos % WW;
        const float coord = (half == 0) ? ((float)j + 0.5f) * (1.f / 180.f)
                                        : ((float)i + 0.5f) * (1.f / 180.f);
        const float arg = (coord * 6.2831855f) / dimt;
        pe[p][half * 128 + 2 * m]     = sinf(arg);
        pe[p][half * 128 + 2 * m + 1] = cosf(arg);
    }
    __syncthreads();
    float acc[24];
#pragma unroll
    for (int p = 0; p < 24; ++p) acc[p] = b1[tid];
    for (int k = 0; k < 256; ++k) {
        const float w = w1[k * 128 + tid];
#pragma unroll
        for (int p = 0; p < 24; ++p) acc[p] += pe[p][k] * w;
    }
#pragma unroll
    for (int p = 0; p < 24; ++p) hid[p][tid] = fmaxf(acc[p], 0.f);
    __syncthreads();
#pragma unroll
    for (int p = 0; p < 24; ++p) acc[p] = b2[tid];
    for (int k = 0; k < 128; ++k) {
        const float w = w2[k * 128 + tid];
#pragma unroll
        for (int p = 0; p < 24; ++p) acc[p] += hid[p][k] * w;
    }
#pragma unroll
    for (int p = 0; p < 24; ++p) kpeT[(size_t)tid * HWN + pos0 + p] = acc[p];
}

// ---------------- gather q0/qpe/q_hm ------------------------------------------
__global__ __launch_bounds__(128) void k_gather(const float* __restrict__ feat,
    const float* __restrict__ kpeT, const float* __restrict__ hm_msk,
    const int* __restrict__ top_idx, float* __restrict__ q0,
    float* __restrict__ qpe, float* __restrict__ qhm)
{
    const int p = blockIdx.x, b = blockIdx.y, c = threadIdx.x;
    const int idx = top_idx[b * 200 + p];
    q0[((size_t)b * 200 + p) * 128 + c]  = feat[((size_t)b * 128 + c) * HWN + idx];
    qpe[((size_t)b * 200 + p) * 128 + c] = kpeT[(size_t)c * HWN + idx];
    if (c < 10)
        qhm[((size_t)b * 10 + c) * 200 + p] = hm_msk[((size_t)b * 10 + c) * HWN + idx];
}

// ---------------- self-attn qkv projection ------------------------------------
__global__ __launch_bounds__(128) void k_proj_self(const float* __restrict__ q0,
    const float* __restrict__ qpe, const float* __restrict__ w,
    const float* __restrict__ bias, float* __restrict__ qh,
    float* __restrict__ kh, float* __restrict__ vh)
{
    __shared__ float in0[128], in1[128];
    const int p = blockIdx.x, b = blockIdx.y, c = threadIdx.x;
    const size_t base = ((size_t)b * 200 + p) * 128;
    const float a = q0[base + c], pe = qpe[base + c];
    in0[c] = a + pe; in1[c] = a;
    __syncthreads();
    float aq = bias[c], ak = bias[128 + c], av = bias[256 + c];
    for (int k = 0; k < 128; ++k) {
        const float i0 = in0[k];
        aq += i0 * w[k * 128 + c];
        ak += i0 * w[16384 + k * 128 + c];
        av += in1[k] * w[32768 + k * 128 + c];
    }
    qh[base + c] = aq; kh[base + c] = ak; vh[base + c] = av;
}

// ---------------- self-attention (200 keys) -----------------------------------
__global__ __launch_bounds__(256) void k_attn_self(const float* __restrict__ qh,
    const float* __restrict__ kh, const float* __restrict__ vh, float* __restrict__ o)
{
    __shared__ float ks[200][16], vs[200][16];
    const int h = blockIdx.x, b = blockIdx.y, tid = threadIdx.x;
    for (int s = tid; s < 3200; s += 256) {
        const int n = s >> 4, d = s & 15;
        ks[n][d] = kh[((size_t)b * 200 + n) * 128 + h * 16 + d];
        vs[n][d] = vh[((size_t)b * 200 + n) * 128 + h * 16 + d];
    }
    __syncthreads();
    if (tid < 200) {
        float q[16];
#pragma unroll
        for (int d = 0; d < 16; ++d)
            q[d] = qh[((size_t)b * 200 + tid) * 128 + h * 16 + d] * 0.25f;
        float mmax = -1e30f, lsum = 0.f, acc[16];
#pragma unroll
        for (int d = 0; d < 16; ++d) acc[d] = 0.f;
        for (int j = 0; j < 200; ++j) {
            float s = 0.f;
#pragma unroll
            for (int d = 0; d < 16; ++d) s += q[d] * ks[j][d];
            const float mn = fmaxf(mmax, s);
            const float corr = __expf(mmax - mn);
            const float pv = __expf(s - mn);
            lsum = lsum * corr + pv;
#pragma unroll
            for (int d = 0; d < 16; ++d) acc[d] = acc[d] * corr + pv * vs[j][d];
            mmax = mn;
        }
#pragma unroll
        for (int d = 0; d < 16; ++d)
            o[((size_t)b * 200 + tid) * 128 + h * 16 + d] = acc[d] / lsum;
    }
}

// ---- out-projection + residual + LN (+ optional fused cross-Q projection) ----
template<int FUSEQ>
__global__ __launch_bounds__(128) void k_proj_ln(const float* __restrict__ src,
    const float* __restrict__ W, const float* __restrict__ bW,
    const float* __restrict__ resid, const float* __restrict__ g,
    const float* __restrict__ lb, float* __restrict__ out,
    const float* __restrict__ qpe, const float* __restrict__ wq,
    const float* __restrict__ bq, float* __restrict__ qout)
{
    __shared__ float sIn[128];
    __shared__ float rbuf[4];
    __shared__ float lnrow[128];
    const int p = blockIdx.x, b = blockIdx.y, c = threadIdx.x;
    const size_t base = ((size_t)b * 200 + p) * 128;
    sIn[c] = src[base + c];
    __syncthreads();
    float v = bW[c] + resid[base + c];
    for (int k = 0; k < 128; ++k) v += sIn[k] * W[k * 128 + c];
    float s = v;
#pragma unroll
    for (int off = 32; off >= 1; off >>= 1) s += __shfl_xor(s, off);
    if ((c & 63) == 0) rbuf[c >> 6] = s;
    __syncthreads();
    const float mean = (rbuf[0] + rbuf[1]) * (1.f / 128.f);
    const float dv = v - mean;
    float s2 = dv * dv;
#pragma unroll
    for (int off = 32; off >= 1; off >>= 1) s2 += __shfl_xor(s2, off);
    if ((c & 63) == 0) rbuf[2 + (c >> 6)] = s2;
    __syncthreads();
    const float var = (rbuf[2] + rbuf[3]) * (1.f / 128.f);
    const float ln = g[c] * dv / sqrtf(var + 1e-5f) + lb[c];
    out[base + c] = ln;
    if (FUSEQ) {
        lnrow[c] = ln + qpe[base + c];
        __syncthreads();
        float a = bq[c];
        for (int k = 0; k < 128; ++k) a += lnrow[k] * wq[k * 128 + c];
        qout[base + c] = a;
    }
}

// ------ cross K/V projection over HW -> fp16-split K [bh][n][2][16],
//        V transposed [bh][2][16][HWN] ----------------------------------------
__global__ __launch_bounds__(256) void k_kv_cross(const float* __restrict__ feat,
    const float* __restrict__ kpeT, const float* __restrict__ w,
    const float* __restrict__ bias, _Float16* __restrict__ khs,
    _Float16* __restrict__ vTs)
{
    __shared__ float as[32][68];
    __shared__ float wk[32][128], wv[32][128];
    const int tid = threadIdx.x, n0 = blockIdx.x * 64, b = blockIdx.y;
    const int cg = tid & 31, ng = tid >> 5;
    float ak[4][8], av[4][8];
#pragma unroll
    for (int i = 0; i < 4; ++i)
#pragma unroll
        for (int j = 0; j < 8; ++j) { ak[i][j] = 0.f; av[i][j] = 0.f; }
    for (int kc = 0; kc < 128; kc += 32) {
        for (int s = tid; s < 2048; s += 256) {
            const int k = s >> 6, n = s & 63;
            float fv = 0.f;
            if (n0 + n < HWN)
                fv = feat[((size_t)b * 128 + kc + k) * HWN + n0 + n]
                   + kpeT[(size_t)(kc + k) * HWN + n0 + n];
            as[k][n] = fv;
        }
        for (int s = tid; s < 4096; s += 256) {
            const int k = s >> 7, c = s & 127;
            wk[k][c] = w[(128 + kc + k) * 128 + c];
            wv[k][c] = w[(256 + kc + k) * 128 + c];
        }
        __syncthreads();
#pragma unroll
        for (int k = 0; k < 32; ++k) {
            const float4 x0 = *(const float4*)&as[k][ng * 8];
            const float4 x1 = *(const float4*)&as[k][ng * 8 + 4];
            const float4 wk4 = *(const float4*)&wk[k][cg * 4];
            const float4 wv4 = *(const float4*)&wv[k][cg * 4];
            float xv[8] = {x0.x, x0.y, x0.z, x0.w, x1.x, x1.y, x1.z, x1.w};
#pragma unroll
            for (int j = 0; j < 8; ++j) {
                ak[0][j] += wk4.x * xv[j]; ak[1][j] += wk4.y * xv[j];
                ak[2][j] += wk4.z * xv[j]; ak[3][j] += wk4.w * xv[j];
                av[0][j] += wv4.x * xv[j]; av[1][j] += wv4.y * xv[j];
                av[2][j] += wv4.z * xv[j]; av[3][j] += wv4.w * xv[j];
            }
        }
        __syncthreads();
    }
    float bk[4], bv[4];
#pragma unroll
    for (int i = 0; i < 4; ++i) {
        bk[i] = bias[128 + cg * 4 + i];
        bv[i] = bias[256 + cg * 4 + i];
    }
    const int h = cg >> 2;            // (cg*4)/16
    const int d0 = (cg * 4) & 15;
    const int bh = b * 8 + h;
    // K: [bh][n][t2][16d] (fp16 split)
#pragma unroll
    for (int j = 0; j < 8; ++j) {
        const int n = n0 + ng * 8 + j;
        if (n < HWN) {
            half4 kh4, kl4;
#pragma unroll
            for (int i = 0; i < 4; ++i) {
                const float v = ak[i][j] + bk[i];
                const _Float16 hh = (_Float16)v;
                kh4[i] = hh;
                kl4[i] = (_Float16)((v - (float)hh) * 256.f);
            }
            _Float16* kp = khs + ((size_t)bh * HWN + n) * 32 + d0;
            *(half4*)kp = kh4;
            *(half4*)(kp + 16) = kl4;
        }
    }
    // V^T: [bh][t2][16d][HWN] (fp16 split)
    const int nb = n0 + ng * 8;
#pragma unroll
    for (int i = 0; i < 4; ++i) {
        half8 vh8, vl8;
#pragma unroll
        for (int j = 0; j < 8; ++j) {
            const float v = av[i][j] + bv[i];
            const _Float16 hh = (_Float16)v;
            vh8[j] = hh;
            vl8[j] = (_Float16)((v - (float)hh) * 256.f);
        }
        _Float16* p0 = vTs + ((size_t)(bh * 2 + 0) * 16 + d0 + i) * HWN + nb;
        _Float16* p1 = vTs + ((size_t)(bh * 2 + 1) * 16 + d0 + i) * HWN + nb;
        if (nb + 8 <= HWN) {
            *(half8*)p0 = vh8;
            *(half8*)p1 = vl8;
        } else {
#pragma unroll
            for (int j = 0; j < 8; ++j)
                if (nb + j < HWN) { p0[j] = vh8[j]; p1[j] = vl8[j]; }
        }
    }
}

// ------ MFMA flash cross-attention (swapped QK^T, swapped PV), split-K --------
// 1-wave blocks, grid (7 qtile, 16 bh, KSPLIT). fp16 two-term split on K,Q,V.
__global__ __launch_bounds__(64) void k_flash(const float* __restrict__ qh,
    const _Float16* __restrict__ khs, const _Float16* __restrict__ vTs,
    float* __restrict__ o_part, float* __restrict__ m_part, float* __restrict__ l_part)
{
    const int qt = blockIdx.x, bh = blockIdx.y, ksid = blockIdx.z;
    const int b = bh >> 3, h = bh & 7;
    const int l = threadIdx.x;
    const int l31 = l & 31, kb = l >> 5;
    const int kb4 = kb * 4;
    const int q = qt * 32 + l31;
    const float inv256 = 1.f / 256.f;

    // Q B-fragments (pre-scaled 0.25, fp16 split)
    half8 qbh, qbl;
    {
        float qv[8];
        if (q < 200) {
            const float* qp = qh + ((size_t)b * 200 + q) * 128 + h * 16 + kb * 8;
#pragma unroll
            for (int j = 0; j < 8; ++j) qv[j] = qp[j] * 0.25f;
        } else {
#pragma unroll
            for (int j = 0; j < 8; ++j) qv[j] = 0.f;
        }
#pragma unroll
        for (int j = 0; j < 8; ++j) {
            const _Float16 hh = (_Float16)qv[j];
            qbh[j] = hh;
            qbl[j] = (_Float16)((qv[j] - (float)hh) * 256.f);
        }
    }

    const int nBase = ksid * (HWN / KSPLIT), nEnd = nBase + (HWN / KSPLIT);
    float m = -1e30f, lsum = 0.f;
    f32x16 acc3 = {}, acc4 = {};
    const size_t kbase = (size_t)bh * HWN;
    const size_t vb0 = ((size_t)(bh * 2 + 0) * 16 + l31) * (size_t)HWN;
    const size_t vb1 = ((size_t)(bh * 2 + 1) * 16 + l31) * (size_t)HWN;

    for (int c0 = nBase; c0 < nEnd; c0 += 32) {
        // K A-frags: row=l31 (k-in-tile), kslot d = kb*8+j
        int kcol = c0 + l31; if (kcol >= HWN) kcol = HWN - 1;
        const _Float16* kp = khs + (kbase + kcol) * 32 + kb * 8;
        const half8 kah = *(const half8*)kp;
        const half8 kal = *(const half8*)(kp + 16);
        f32x16 a1 = {}, a2 = {};
        a1 = MFMA16(kah, qbh, a1);
        a2 = MFMA16(kah, qbl, a2);
        a2 = MFMA16(kal, qbh, a2);
        // scores (D: col=q=l31, row=k=(r&3)+8*(r>>2)+4*kb) + boundary mask
        float s[16];
        float cm = -1e30f;
#pragma unroll
        for (int r = 0; r < 16; ++r) {
            const int kk = (r & 3) + 8 * (r >> 2) + kb4;
            float v = a1[r] + a2[r] * inv256;
            v = (c0 + kk < nEnd) ? v : -1e30f;
            s[r] = v;
            cm = fmaxf(cm, v);
        }
        cm = fmaxf(cm, __shfl_xor(cm, 32));
        const float mn = fmaxf(m, cm);
        const float corr = __expf(m - mn);
        lsum *= corr;
#pragma unroll
        for (int r = 0; r < 16; ++r) { acc3[r] *= corr; acc4[r] *= corr; }
        float p[16];
#pragma unroll
        for (int r = 0; r < 16; ++r) { p[r] = __expf(s[r] - mn); lsum += p[r]; }
        m = mn;
        // pack P to fp16, exchange across kb-half lanes, build P^T B-frags
        const u32 o01 = pkh(p[0], p[1]),  o23 = pkh(p[2], p[3]);
        const u32 o45 = pkh(p[4], p[5]),  o67 = pkh(p[6], p[7]);
        const u32 o89 = pkh(p[8], p[9]),  oAB = pkh(p[10], p[11]);
        const u32 oCD = pkh(p[12], p[13]), oEF = pkh(p[14], p[15]);
        const u32 x01 = __shfl_xor(o01, 32), x23 = __shfl_xor(o23, 32);
        const u32 x45 = __shfl_xor(o45, 32), x67 = __shfl_xor(o67, 32);
        const u32 x89 = __shfl_xor(o89, 32), xAB = __shfl_xor(oAB, 32);
        const u32 xCD = __shfl_xor(oCD, 32), xEF = __shfl_xor(oEF, 32);
        const half8 pb0 = (kb == 0) ? mkh8(o01, o23, x01, x23) : mkh8(x45, x67, o45, o67);
        const half8 pb1 = (kb == 0) ? mkh8(o89, oAB, x89, xAB) : mkh8(xCD, xEF, oCD, oEF);
        // V^T A-frags: row=l31=d (valid <16), kslot = khalf*16 + kb*8 + j
        half8 vh0 = {}, vl0 = {}, vh1 = {}, vl1 = {};
        if (l31 < 16) {
            const int cA = c0 + kb * 8;
            const int cB = c0 + 16 + kb * 8;
            if (cB + 8 <= HWN) {
                vh0 = *(const half8*)(vTs + vb0 + cA);
                vh1 = *(const half8*)(vTs + vb0 + cB);
                vl0 = *(const half8*)(vTs + vb1 + cA);
                vl1 = *(const half8*)(vTs + vb1 + cB);
            } else {
#pragma unroll
                for (int j = 0; j < 8; ++j) {
                    if (cA + j < HWN) { vh0[j] = vTs[vb0 + cA + j]; vl0[j] = vTs[vb1 + cA + j]; }
                    if (cB + j < HWN) { vh1[j] = vTs[vb0 + cB + j]; vl1[j] = vTs[vb1 + cB + j]; }
                }
            }
        }
        acc3 = MFMA16(vh0, pb0, acc3);
        acc3 = MFMA16(vh1, pb1, acc3);
        acc4 = MFMA16(vl0, pb0, acc4);
        acc4 = MFMA16(vl1, pb1, acc4);
    }

    const float lt = lsum + __shfl_xor(lsum, 32);
    if (q < 200) {
        const size_t pbase = ((size_t)bh * KSPLIT + ksid) * 200 + q;
        if (kb == 0) { m_part[pbase] = m; l_part[pbase] = lt; }
#pragma unroll
        for (int r = 0; r < 8; ++r) {
            const int d = (r & 3) + 8 * (r >> 2) + kb4;
            o_part[pbase * 16 + d] = acc3[r] + acc4[r] * inv256;
        }
    }
}

// ---------------- merge flash splits ------------------------------------------
__global__ __launch_bounds__(64) void k_merge(const float* __restrict__ o_part,
    const float* __restrict__ m_part, const float* __restrict__ l_part,
    float* __restrict__ o_c)
{
    const int row = blockIdx.x, bh = blockIdx.y;
    const int b = bh >> 3, h = bh & 7;
    const int lane = threadIdx.x;
    float M = -1e30f;
#pragma unroll
    for (int k = 0; k < KSPLIT; ++k)
        M = fmaxf(M, m_part[((size_t)bh * KSPLIT + k) * 200 + row]);
    float L = 0.f;
#pragma unroll
    for (int k = 0; k < KSPLIT; ++k)
        L += l_part[((size_t)bh * KSPLIT + k) * 200 + row]
           * __expf(m_part[((size_t)bh * KSPLIT + k) * 200 + row] - M);
    if (lane < 16) {
        float o = 0.f;
#pragma unroll
        for (int k = 0; k < KSPLIT; ++k)
            o += o_part[(((size_t)bh * KSPLIT + k) * 200 + row) * 16 + lane]
               * __expf(m_part[((size_t)bh * KSPLIT + k) * 200 + row] - M);
        o_c[((size_t)b * 200 + row) * 128 + h * 16 + lane] = o / L;
    }
}

// ---------------- FFN + residual + LN3 ----------------------------------------
__global__ __launch_bounds__(256) void k_ffn_ln(const float* __restrict__ x,
    const float* __restrict__ w1, const float* __restrict__ b1,
    const float* __restrict__ w2, const float* __restrict__ b2,
    const float* __restrict__ g, const float* __restrict__ lb, float* __restrict__ out)
{
    __shared__ float xr[128];
    __shared__ float hs[256];
    __shared__ float rbuf[8];
    const int p = blockIdx.x, b = blockIdx.y, t = threadIdx.x;
    const size_t base = ((size_t)b * 200 + p) * 128;
    if (t < 128) xr[t] = x[base + t];
    __syncthreads();
    float hv = b1[t];
    for (int k = 0; k < 128; ++k) hv += xr[k] * w1[k * 256 + t];
    hs[t] = fmaxf(hv, 0.f);
    __syncthreads();
    float v = 0.f;
    if (t < 128) {
        v = b2[t] + xr[t];
        for (int k = 0; k < 256; ++k) v += hs[k] * w2[k * 128 + t];
    }
    float s = (t < 128) ? v : 0.f;
#pragma unroll
    for (int off = 32; off >= 1; off >>= 1) s += __shfl_xor(s, off);
    if ((t & 63) == 0) rbuf[t >> 6] = s;
    __syncthreads();
    const float mean = (rbuf[0] + rbuf[1] + rbuf[2] + rbuf[3]) * (1.f / 128.f);
    const float dv = v - mean;
    float s2 = (t < 128) ? dv * dv : 0.f;
#pragma unroll
    for (int off = 32; off >= 1; off >>= 1) s2 += __shfl_xor(s2, off);
    if ((t & 63) == 0) rbuf[4 + (t >> 6)] = s2;
    __syncthreads();
    const float var = (rbuf[4] + rbuf[5] + rbuf[6] + rbuf[7]) * (1.f / 128.f);
    if (t < 128) out[base + t] = g[t] * dv / sqrtf(var + 1e-5f) + lb[t];
}

// ---------------- separate heads: conv1 + BN + ReLU ---------------------------
__global__ __launch_bounds__(256) void k_head_h(const float* __restrict__ q3,
    const float* __restrict__ w1, const float* __restrict__ b1,
    const float* __restrict__ g, const float* __restrict__ beta,
    float* __restrict__ h_all)
{
    __shared__ float qw[128][32];
    const int pt = blockIdx.x, ih = blockIdx.y, b = blockIdx.z;
    const int tid = threadIdx.x;
    for (int s = tid; s < 4096; s += 256) {
        const int c = s & 127, wg = s >> 7;
        const int pg = pt * 24 - 1 + wg;
        qw[c][wg] = ((unsigned)pg < 200u) ? q3[((size_t)b * 200 + pg) * 128 + c] : 0.f;
    }
    __syncthreads();
    const int c = tid & 127, half = tid >> 7;
    float acc[12];
#pragma unroll
    for (int pp = 0; pp < 12; ++pp) acc[pp] = 0.f;
    const float* wbase = w1 + ((size_t)ih * 128 + c) * 384;
    for (int cin = 0; cin < 128; ++cin) {
        const float4* qp = (const float4*)&qw[cin][half * 12];
        const float4 a0 = qp[0], a1 = qp[1], a2 = qp[2], a3 = qp[3];
        float xr[16] = {a0.x, a0.y, a0.z, a0.w, a1.x, a1.y, a1.z, a1.w,
                        a2.x, a2.y, a2.z, a2.w, a3.x, a3.y, a3.z, a3.w};
        const float w0 = wbase[cin * 3], w1v = wbase[cin * 3 + 1], w2v = wbase[cin * 3 + 2];
#pragma unroll
        for (int pp = 0; pp < 12; ++pp)
            acc[pp] += xr[pp] * w0 + xr[pp + 1] * w1v + xr[pp + 2] * w2v;
    }
    const float bs = b1[ih * 128 + c], gg = g[ih * 128 + c], bt = beta[ih * 128 + c];
#pragma unroll
    for (int pp = 0; pp < 12; ++pp) {
        const int p = pt * 24 + half * 12 + pp;
        if (p < 200)
            h_all[(((size_t)b * 6 + ih) * 128 + c) * 200 + p] =
                fmaxf(gg * (acc[pp] + bs) + bt, 0.f);
    }
}

// ---------------- separate heads: conv2 + hm-score fusion ---------------------
__global__ void k_head_out(const float* __restrict__ h_all, const float* __restrict__ w2,
    const float* __restrict__ b2, const float* __restrict__ qhm, float* __restrict__ out)
{
    const int gid = blockIdx.x * 256 + threadIdx.x;
    if (gid >= 8000) return;
    const int p = gid % 200, rem = gid / 200, row = rem % 20, b = rem / 20;
    int i, oo;
    if (row < 2)       { i = 0; oo = row; }
    else if (row < 3)  { i = 1; oo = row - 2; }
    else if (row < 6)  { i = 2; oo = row - 3; }
    else if (row < 8)  { i = 3; oo = row - 6; }
    else if (row < 10) { i = 4; oo = row - 8; }
    else               { i = 5; oo = row - 10; }
    const float* hb = h_all + (((size_t)b * 6 + i) * 128) * 200;
    const float* wb = w2 + ((size_t)i * 10 + oo) * 384;
    float acc = b2[i * 10 + oo];
    for (int c = 0; c < 128; ++c) {
        const float* hr = hb + (size_t)c * 200 + p;
        const float x0 = (p > 0) ? hr[-1] : 0.f;
        const float x1 = hr[0];
        const float x2 = (p < 199) ? hr[1] : 0.f;
        acc += x0 * wb[c * 3] + x1 * wb[c * 3 + 1] + x2 * wb[c * 3 + 2];
    }
    if (i == 5) acc += qhm[((size_t)b * 10 + oo) * 200 + p];
    out[((size_t)b * 20 + row) * 200 + p] = acc;
}

// ---------------- launcher ----------------------------------------------------
extern "C" void kernel_launch(void* const* d_in, const int* in_sizes, int n_in,
                              void* d_out, int out_size, void* d_ws, size_t ws_size,
                              hipStream_t stream) {
    (void)in_sizes; (void)n_in; (void)out_size; (void)ws_size;
    const float* x        = (const float*)d_in[0];
    const float* w_shared = (const float*)d_in[1];
    const float* b_shared = (const float*)d_in[2];
    const float* w_hm1    = (const float*)d_in[3];
    const float* b_hm1    = (const float*)d_in[4];
    const float* g_hm1    = (const float*)d_in[5];
    const float* beta_hm1 = (const float*)d_in[6];
    const float* w_hm2    = (const float*)d_in[7];
    const float* b_hm2    = (const float*)d_in[8];
    const float* w_be1    = (const float*)d_in[15];
    const float* b_be1    = (const float*)d_in[16];
    const float* w_be2    = (const float*)d_in[17];
    const float* b_be2    = (const float*)d_in[18];
    const float* w_attn_s = (const float*)d_in[19];
    const float* b_attn_s = (const float*)d_in[20];
    const float* w_out_s  = (const float*)d_in[21];
    const float* b_out_s  = (const float*)d_in[22];
    const float* w_attn_c = (const float*)d_in[23];
    const float* b_attn_c = (const float*)d_in[24];
    const float* w_out_c  = (const float*)d_in[25];
    const float* b_out_c  = (const float*)d_in[26];
    const float* ln1_g    = (const float*)d_in[27];
    const float* ln1_b    = (const float*)d_in[28];
    const float* ln2_g    = (const float*)d_in[29];
    const float* ln2_b    = (const float*)d_in[30];
    const float* ln3_g    = (const float*)d_in[31];
    const float* ln3_b    = (const float*)d_in[32];
    const float* w_ff1    = (const float*)d_in[33];
    const float* b_ff1    = (const float*)d_in[34];
    const float* w_ff2    = (const float*)d_in[35];
    const float* b_ff2    = (const float*)d_in[36];
    const float* w_head1  = (const float*)d_in[37];
    const float* b_head1  = (const float*)d_in[38];
    const float* g_head1  = (const float*)d_in[39];
    const float* bt_head1 = (const float*)d_in[40];
    const float* w_head2  = (const float*)d_in[41];
    const float* b_head2  = (const float*)d_in[42];

    char* ws = (char*)d_ws;
    size_t off = 0;
    auto alloc = [&](size_t bytes) { size_t o = off; off += (bytes + 255) & ~(size_t)255; return o; };
    _Float16* wimg_s  = (_Float16*)(ws + alloc((size_t)12*9*16384));
    _Float16* wimg_h1 = (_Float16*)(ws + alloc((size_t)4*9*16384));
    _Float16* wimg_hm = (_Float16*)(ws + alloc((size_t)4*9*2048*2));
    char*     xs1reg  = (ws + alloc((size_t)2*180*12*2*180*32*2));   // 99.5 MB, dies after conv1
    _Float16* xs1     = (_Float16*)xs1reg;
    _Float16* xs2     = (_Float16*)(ws + alloc((size_t)2*180*4*2*180*32*2));
    float* feat   = (float*)(ws + alloc((size_t)2*128*HWN*4));
    _Float16* khs = (_Float16*)(ws + alloc((size_t)16*HWN*32*2));    // K fp16 split
    float* kpeT   = (float*)(ws + alloc((size_t)128*HWN*4));
    int*   topidx = (int*)  (ws + alloc((size_t)2*200*4));
    unsigned* hist  = (unsigned*)(ws + alloc((size_t)2*TKBINS*4));   // 2 MB
    unsigned* pivot = (unsigned*)(ws + alloc((size_t)2*4));
    unsigned long long* cand = (unsigned long long*)(ws + alloc((size_t)2*4096*8));
    unsigned* ccnt  = (unsigned*)(ws + alloc((size_t)2*4));
    float* q0     = (float*)(ws + alloc((size_t)2*200*128*4));
    float* qpe    = (float*)(ws + alloc((size_t)2*200*128*4));
    float* q_hm   = (float*)(ws + alloc((size_t)2*10*200*4));
    float* qh_s   = (float*)(ws + alloc((size_t)2*200*128*4));
    float* kh_s   = (float*)(ws + alloc((size_t)2*200*128*4));
    float* vh_s   = (float*)(ws + alloc((size_t)2*200*128*4));
    float* o_s    = (float*)(ws + alloc((size_t)2*200*128*4));
    float* q1n    = (float*)(ws + alloc((size_t)2*200*128*4));
    float* qh_c   = (float*)(ws + alloc((size_t)2*200*128*4));
    float* o_c    = (float*)(ws + alloc((size_t)2*200*128*4));
    float* q2n    = (float*)(ws + alloc((size_t)2*200*128*4));
    float* q3     = (float*)(ws + alloc((size_t)2*200*128*4));
    float* h_all  = (float*)(ws + alloc((size_t)2*6*128*200*4));

    // buffers aliased into xs1's region (first written after conv1 consumed xs1)
    size_t xo = 0;
    auto xalloc = [&](size_t bytes) { size_t o = xo; xo += (bytes + 255) & ~(size_t)255; return o; };
    _Float16* vTs = (_Float16*)(xs1reg + xalloc((size_t)16*2*16*HWN*2));  // V^T fp16 split
    float* hm_raw = (float*)(xs1reg + xalloc((size_t)2*10*HWN*4));
    float* hm_msk = (float*)(xs1reg + xalloc((size_t)2*10*HWN*4));
    float* o_part = (float*)(xs1reg + xalloc((size_t)16*KSPLIT*200*16*4));
    float* m_part = (float*)(xs1reg + xalloc((size_t)16*KSPLIT*200*4));
    float* l_part = (float*)(xs1reg + xalloc((size_t)16*KSPLIT*200*4));
    _Float16* h1s = (_Float16*)(xs1reg + xalloc((size_t)2*180*4*2*180*32*2)); // 33.2 MB

    k_tkzero<<<(2*TKBINS)/1024, 1024, 0, stream>>>(hist, ccnt);
    k_wsplit<<<(12*9*8192 + 255)/256, 256, 0, stream>>>(w_shared, wimg_s, CINN);
    k_wsplit<<<(4*9*8192 + 255)/256, 256, 0, stream>>>(w_hm1, wimg_h1, 128);
    k_wsplit_hm<<<(4*9*2048 + 255)/256, 256, 0, stream>>>(w_hm2, wimg_hm);
    k_xsplit<<<dim3(12, 180, 2), 256, 0, stream>>>(x, xs1, CINN, 12);
    k_kpe<<<HWN/24, 128, 0, stream>>>(w_be1, b_be1, w_be2, b_be2, kpeT);
    k_conv<12, 0, 1, 1><<<dim3(6, 90, 2), 256, 0, stream>>>(xs1, wimg_s, b_shared, nullptr, nullptr, feat, xs2);
    k_conv<4, 1, 0, 1><<<dim3(6, 90, 2), 256, 0, stream>>>(xs2, wimg_h1, b_hm1, g_hm1, beta_hm1, nullptr, h1s);
    k_convhm2m<4><<<dim3(3, 90, 2), 256, 0, stream>>>(h1s, wimg_hm, b_hm2, hm_raw);
    k_nms<<<(2*10*HWN + 255)/256, 256, 0, stream>>>(hm_raw, hm_msk, hist);
    k_tkscan<<<2, 1024, 0, stream>>>(hist, pivot);
    k_tkcollect<<<dim3(317, 2), 1024, 0, stream>>>(hm_msk, pivot, cand, ccnt);
    k_tksort<<<2, 1024, 0, stream>>>(cand, ccnt, topidx);
    k_gather<<<dim3(200, 2), 128, 0, stream>>>(feat, kpeT, hm_msk, topidx, q0, qpe, q_hm);
    k_proj_self<<<dim3(200, 2), 128, 0, stream>>>(q0, qpe, w_attn_s, b_attn_s, qh_s, kh_s, vh_s);
    k_attn_self<<<dim3(8, 2), 256, 0, stream>>>(qh_s, kh_s, vh_s, o_s);
    k_proj_ln<1><<<dim3(200, 2), 128, 0, stream>>>(o_s, w_out_s, b_out_s, q0, ln1_g, ln1_b, q1n,
                                                   qpe, w_attn_c, b_attn_c, qh_c);
    k_kv_cross<<<dim3(507, 2), 256, 0, stream>>>(feat, kpeT, w_attn_c, b_attn_c, khs, vTs);
    k_flash<<<dim3(7, 16, KSPLIT), 64, 0, stream>>>(qh_c, khs, vTs, o_part, m_part, l_part);
    k_merge<<<dim3(200, 16), 64, 0, stream>>>(o_part, m_part, l_part, o_c);
    k_proj_ln<0><<<dim3(200, 2), 128, 0, stream>>>(o_c, w_out_c, b_out_c, q1n, ln2_g, ln2_b, q2n,
                                                   nullptr, nullptr, nullptr, nullptr);
    k_ffn_ln<<<dim3(200, 2), 256, 0, stream>>>(q2n, w_ff1, b_ff1, w_ff2, b_ff2, ln3_g, ln3_b, q3);
    k_head_h<<<dim3(9, 6, 2), 256, 0, stream>>>(q3, w_head1, b_head1, g_head1, bt_head1, h_all);
    k_head_out<<<32, 256, 0, stream>>>(h_all, w_head2, b_head2, q_hm, (float*)d_out);
}

// Round 14
// 935.500 us; speedup vs baseline: 1.0624x; 1.0624x over previous
//
#include <hip/hip_runtime.h>

#define HH 180
#define WW 180
#define HWN 32400
#define CC 128
#define CINN 384
#define KK 10
#define PP 200
#define NHH 8
#define BB 2
#define NTOT 324000  // K*H*W per batch
#define TKBINS (1 << 18)
#define KSPLIT 16

typedef _Float16 half8 __attribute__((ext_vector_type(8)));
typedef _Float16 half4 __attribute__((ext_vector_type(4)));
typedef float f32x16 __attribute__((ext_vector_type(16)));
typedef unsigned int u32;

static __device__ __forceinline__ f32x16 MFMA16(half8 a, half8 b, f32x16 c) {
    return __builtin_amdgcn_mfma_f32_32x32x16_f16(a, b, c, 0, 0, 0);
}
static __device__ __forceinline__ half8 mkh8(u32 a, u32 b, u32 c, u32 d) {
    union { u32 u[4]; half8 h; } x; x.u[0] = a; x.u[1] = b; x.u[2] = c; x.u[3] = d; return x.h;
}
static __device__ __forceinline__ u32 pkh(float a, float b) {
    union { _Float16 h[2]; u32 u; } x; x.h[0] = (_Float16)a; x.h[1] = (_Float16)b; return x.u;
}

// ------ weight split image: [bidx=ch*9+tap][t2][q4][cout128][8 halves] --------
__global__ void k_wsplit(const float* __restrict__ w, _Float16* __restrict__ img, int cint) {
    const int e = blockIdx.x * 256 + threadIdx.x;
    const int total = (cint / 32) * 9 * 8192;
    if (e >= total) return;
    const int ii = e & 7, cout = (e >> 3) & 127, q = (e >> 10) & 3, t = (e >> 12) & 1;
    const int bidx = e >> 13, tap = bidx % 9, ch = bidx / 9;
    const int cin = ch * 32 + q * 8 + ii;
    const float v = w[((size_t)cout * cint + cin) * 9 + tap];
    const _Float16 h = (_Float16)v;
    img[e] = (t == 0) ? h : (_Float16)((v - (float)h) * 256.f);
}

// ------ hm2 weight split image: [bidx][t2][q4][cout32(10 real)][8 halves] -----
__global__ void k_wsplit_hm(const float* __restrict__ w, _Float16* __restrict__ img) {
    const int e = blockIdx.x * 256 + threadIdx.x;
    const int total = 4 * 9 * 2048;
    if (e >= total) return;
    const int ii = e & 7, co = (e >> 3) & 31, q = (e >> 8) & 3, t = (e >> 10) & 1;
    const int bidx = e >> 11, tap = bidx % 9, ch = bidx / 9;
    const int cin = ch * 32 + q * 8 + ii;
    const float v = (co < 10) ? w[((size_t)co * 128 + cin) * 9 + tap] : 0.f;
    const _Float16 h = (_Float16)v;
    img[e] = (t == 0) ? h : (_Float16)((v - (float)h) * 256.f);
}

// ------ x transpose+split: x[b][cin][y][x] -> xs[b][y][ch][t][x][cin32] -------
__global__ __launch_bounds__(256) void k_xsplit(const float* __restrict__ x,
    _Float16* __restrict__ out, int CIN, int NCH)
{
    __shared__ float tile[32][184];
    const int ch = blockIdx.x, y = blockIdx.y, b = blockIdx.z;
    const int tid = threadIdx.x;
    for (int s = tid; s < 32 * 180; s += 256) {
        const int c = s / 180, px = s % 180;
        tile[c][px] = x[(((size_t)b * CIN + ch * 32 + c) * HH + y) * WW + px];
    }
    __syncthreads();
    const size_t pbase = ((((size_t)b * 180 + y) * NCH + ch) * 2) * (180 * 32);
    for (int tt = tid; tt < 1440; tt += 256) {
        const int t = tt / 720, u = tt % 720, px = u >> 2, q = u & 3;
        half8 hv;
#pragma unroll
        for (int j = 0; j < 8; ++j) {
            const float v = tile[q * 8 + j][px];
            const _Float16 h = (_Float16)v;
            hv[j] = (t == 0) ? h : (_Float16)((v - (float)h) * 256.f);
        }
        *(half8*)(out + pbase + (size_t)t * (180 * 32) + px * 32 + q * 8) = hv;
    }
}

// ------ MFMA 3x3 conv: cout-split blocks, direct-from-L2 W with 1-tap prefetch
template<int NCH, int EPI, int WRITEF, int SPLIT>
__global__ __launch_bounds__(256, 3) void k_conv(
    const _Float16* __restrict__ xs, const _Float16* __restrict__ wimg,
    const float* __restrict__ bias, const float* __restrict__ g,
    const float* __restrict__ beta, float* __restrict__ outf,
    _Float16* __restrict__ outs)
{
    __shared__ __align__(16) char sh[36992];   // A 33792 | C epilogue 36864
    const int tid = threadIdx.x;
    const int b = blockIdx.z >> 1, ch2 = blockIdx.z & 1;
    const int oy0 = blockIdx.y * 2, ox0 = blockIdx.x * 64;
    const int wave = tid >> 6, l = tid & 63;
    const int wr = wave >> 1, nh = wave & 1;
    const int l31 = l & 31, kb = l >> 5;

    f32x16 acc1[2] = {};
    f32x16 acc2[2] = {};

    int wofs[2][2];
#pragma unroll
    for (int t = 0; t < 2; ++t)
#pragma unroll
        for (int s = 0; s < 2; ++s)
            wofs[t][s] = (((t * 4) + (s * 2 + kb)) * 128 + ch2 * 64 + nh * 32 + l31) * 16;

    half8 bwC[2][2], bwN[2][2];
#pragma unroll
    for (int t = 0; t < 2; ++t)
#pragma unroll
        for (int s = 0; s < 2; ++s)
            bwC[t][s] = *(const half8*)((const char*)wimg + wofs[t][s]);

#pragma unroll 1
    for (int ch = 0; ch < NCH; ++ch) {
        if (ch) __syncthreads();
#pragma unroll
        for (int k = 0; k < 9; ++k) {
            const int tt = tid + k * 256;
            if (tt < 2112) {
                const int seg = tt / 264, u = tt - seg * 264;
                const int t = seg >> 2, r = seg & 3;
                const int i = u >> 2, q = u & 3;
                const int gy = oy0 - 1 + r, gx = ox0 - 1 + i;
                uint4 v = {0u, 0u, 0u, 0u};
                if ((unsigned)gy < 180u && (unsigned)gx < 180u)
                    v = *(const uint4*)((const char*)xs +
                        (((((size_t)b * 180 + gy) * NCH + ch) * 2 + t) * 180 + gx) * 64 + q * 16);
                *(uint4*)(sh + ((t * 4 + r) * 4 + q) * 1056 + i * 16) = v;
            }
        }
        __syncthreads();
#pragma unroll
        for (int tap = 0; tap < 9; ++tap) {
            const int bidx = ch * 9 + tap;
            const bool pf = (bidx + 1 < NCH * 9);
            if (pf) {
                const char* wn = (const char*)wimg + (size_t)(bidx + 1) * 16384;
#pragma unroll
                for (int t = 0; t < 2; ++t)
#pragma unroll
                    for (int s = 0; s < 2; ++s)
                        bwN[t][s] = *(const half8*)(wn + wofs[t][s]);
            }
            const int ky = tap / 3, kx = tap % 3;
            const int rr = wr + ky;
#pragma unroll
            for (int s = 0; s < 2; ++s) {
                const int q = s * 2 + kb;
                half8 ah[2], al[2];
#pragma unroll
                for (int mf = 0; mf < 2; ++mf) {
                    const int io = (mf * 32 + l31 + kx) * 16;
                    ah[mf] = *(const half8*)(sh + ((rr) * 4 + q) * 1056 + io);
                    al[mf] = *(const half8*)(sh + ((4 + rr) * 4 + q) * 1056 + io);
                }
#pragma unroll
                for (int mf = 0; mf < 2; ++mf) {
                    acc1[mf] = MFMA16(ah[mf], bwC[0][s], acc1[mf]);
                    acc2[mf] = MFMA16(ah[mf], bwC[1][s], acc2[mf]);
                    acc2[mf] = MFMA16(al[mf], bwC[0][s], acc2[mf]);
                }
            }
            if (pf) {
#pragma unroll
                for (int t = 0; t < 2; ++t)
#pragma unroll
                    for (int s = 0; s < 2; ++s)
                        bwC[t][s] = bwN[t][s];
            }
        }
    }

    // epilogue: single phase through C [64co][2r][72pad] (reuses sh)
    float* C = (float*)sh;
    const float inv256 = 1.f / 256.f;
    __syncthreads();
#pragma unroll
    for (int mf = 0; mf < 2; ++mf)
#pragma unroll
        for (int reg = 0; reg < 16; ++reg) {
            const int px = mf * 32 + (reg & 3) + 8 * (reg >> 2) + 4 * kb;
            const int co = nh * 32 + l31;
            C[(co * 2 + wr) * 72 + px] = acc1[mf][reg] + acc2[mf][reg] * inv256;
        }
    __syncthreads();
    if (WRITEF) {
        for (int tt = tid; tt < 2048; tt += 256) {
            const int co = tt >> 5, rem = tt & 31, r = rem >> 4, qx = rem & 15;
            const int gx = ox0 + qx * 4;
            if (gx < WW) {
                float4 v = *(const float4*)&C[(co * 2 + r) * 72 + qx * 4];
                const int cout = ch2 * 64 + co;
                const float bv = bias[cout];
                v.x += bv; v.y += bv; v.z += bv; v.w += bv;
                if (EPI) {
                    const float gg = g[cout], bb = beta[cout];
                    v.x = fmaxf(gg * v.x + bb, 0.f); v.y = fmaxf(gg * v.y + bb, 0.f);
                    v.z = fmaxf(gg * v.z + bb, 0.f); v.w = fmaxf(gg * v.w + bb, 0.f);
                }
                *(float4*)(outf + (((size_t)b * 128 + cout) * HH + oy0 + r) * WW + gx) = v;
            }
        }
    }
    if (SPLIT) {
        for (int tt = tid; tt < 1024; tt += 256) {
            const int q = tt & 3, px = (tt >> 2) & 63, c2 = (tt >> 8) & 1, r = tt >> 9;
            const int gx = ox0 + px;
            if (gx < WW) {
                const int chg = ch2 * 2 + c2;
                half8 hv, lv;
#pragma unroll
                for (int j = 0; j < 8; ++j) {
                    const int col = c2 * 32 + q * 8 + j;
                    const int cout = ch2 * 64 + col;
                    float v = C[(col * 2 + r) * 72 + px] + bias[cout];
                    if (EPI) v = fmaxf(g[cout] * v + beta[cout], 0.f);
                    const _Float16 h = (_Float16)v;
                    hv[j] = h;
                    lv[j] = (_Float16)((v - (float)h) * 256.f);
                }
                char* dst = (char*)outs +
                    ((((size_t)b * 180 + (oy0 + r)) * 4 + chg) * 2) * 11520 + gx * 64 + q * 16;
                *(half8*)dst = hv;
                *(half8*)(dst + 11520) = lv;
            }
        }
    }
}

// ------ heatmap conv2 (128->10) via MFMA split + sigmoid ----------------------
template<int NCH>
__global__ __launch_bounds__(256, 3) void k_convhm2m(
    const _Float16* __restrict__ xs, const _Float16* __restrict__ wimg,
    const float* __restrict__ bias, float* __restrict__ hm_raw)
{
    __shared__ __align__(16) char sh[36992];
    const int tid = threadIdx.x;
    const int b = blockIdx.z;
    const int oy0 = blockIdx.y * 2, ox0 = blockIdx.x * 64;
    const int wave = tid >> 6, l = tid & 63;
    const int wr = wave >> 1, dup = wave & 1;
    const int l31 = l & 31, kb = l >> 5;

    f32x16 acc1[2] = {};
    f32x16 acc2[2] = {};

    const int q = dup * 2 + kb;
    int wofs[2];
#pragma unroll
    for (int t = 0; t < 2; ++t)
        wofs[t] = ((t * 4 + q) * 32 + l31) * 16;

#pragma unroll 1
    for (int ch = 0; ch < NCH; ++ch) {
        if (ch) __syncthreads();
#pragma unroll
        for (int k = 0; k < 9; ++k) {
            const int tt = tid + k * 256;
            if (tt < 2112) {
                const int seg = tt / 264, u = tt - seg * 264;
                const int t = seg >> 2, r = seg & 3;
                const int i = u >> 2, qq = u & 3;
                const int gy = oy0 - 1 + r, gx = ox0 - 1 + i;
                uint4 v = {0u, 0u, 0u, 0u};
                if ((unsigned)gy < 180u && (unsigned)gx < 180u)
                    v = *(const uint4*)((const char*)xs +
                        (((((size_t)b * 180 + gy) * NCH + ch) * 2 + t) * 180 + gx) * 64 + qq * 16);
                *(uint4*)(sh + ((t * 4 + r) * 4 + qq) * 1056 + i * 16) = v;
            }
        }
        __syncthreads();
        const char* wb = (const char*)wimg + (size_t)ch * 9 * 4096;
#pragma unroll
        for (int tap = 0; tap < 9; ++tap) {
            const char* wt = wb + tap * 4096;
            const half8 bw0 = *(const half8*)(wt + wofs[0]);
            const half8 bw1 = *(const half8*)(wt + wofs[1]);
            const int ky = tap / 3, kx = tap % 3;
            const int rr = wr + ky;
#pragma unroll
            for (int mf = 0; mf < 2; ++mf) {
                const int io = (mf * 32 + l31 + kx) * 16;
                const half8 ah = *(const half8*)(sh + ((rr) * 4 + q) * 1056 + io);
                const half8 al = *(const half8*)(sh + ((4 + rr) * 4 + q) * 1056 + io);
                acc1[mf] = MFMA16(ah, bw0, acc1[mf]);
                acc2[mf] = MFMA16(ah, bw1, acc2[mf]);
                acc2[mf] = MFMA16(al, bw0, acc2[mf]);
            }
        }
    }

    // pair-reduce dup0+dup1 through LDS (C1 at 0, C2 at float-offset 4160)
    float* C = (float*)sh;
    __syncthreads();
    if (dup == 0) {
#pragma unroll
        for (int mf = 0; mf < 2; ++mf)
#pragma unroll
            for (int reg = 0; reg < 16; ++reg) {
                const int px = mf * 32 + (reg & 3) + 8 * (reg >> 2) + 4 * kb;
                C[(wr * 32 + l31) * 65 + px] = acc1[mf][reg];
                C[4160 + (wr * 32 + l31) * 65 + px] = acc2[mf][reg];
            }
    }
    __syncthreads();
    if (dup == 1 && l31 < 10) {
        const float inv256 = 1.f / 256.f;
        const float bv = bias[l31];
#pragma unroll
        for (int mf = 0; mf < 2; ++mf)
#pragma unroll
            for (int reg = 0; reg < 16; ++reg) {
                const int px = mf * 32 + (reg & 3) + 8 * (reg >> 2) + 4 * kb;
                const int gx = ox0 + px;
                if (gx < WW) {
                    const float z = (C[(wr * 32 + l31) * 65 + px] + acc1[mf][reg])
                                  + (C[4160 + (wr * 32 + l31) * 65 + px] + acc2[mf][reg]) * inv256
                                  + bv;
                    hm_raw[(((size_t)b * 10 + l31) * HH + oy0 + wr) * WW + gx] =
                        1.f / (1.f + expf(-z));
                }
            }
    }
}

// ---------------- 3x3 local-max NMS mask + fused histogram --------------------
__global__ void k_nms(const float* __restrict__ hm, float* __restrict__ out,
                      unsigned* __restrict__ hist) {
    int i = blockIdx.x * 256 + threadIdx.x;
    if (i >= BB * KK * HWN) return;
    int xx = i % WW, yy = (i / WW) % HH, ck = i / HWN;
    float v = hm[i], m = v;
    for (int dy = -1; dy <= 1; ++dy) {
        int ny = yy + dy;
        if ((unsigned)ny >= (unsigned)HH) continue;
        for (int dx = -1; dx <= 1; ++dx) {
            int nx = xx + dx;
            if ((unsigned)nx >= (unsigned)WW) continue;
            m = fmaxf(m, hm[(size_t)ck * HWN + ny * WW + nx]);
        }
    }
    const float mv = (v == m) ? v : 0.f;
    out[i] = mv;
    const unsigned key = __float_as_uint(mv);
    if (key != 0u)
        atomicAdd(&hist[(size_t)(i / NTOT) * TKBINS + (key >> 14)], 1u);
}

// ---------------- exact top-200: parallel pipeline ----------------------------
__global__ __launch_bounds__(1024) void k_tkzero(unsigned* __restrict__ hist,
                                                 unsigned* __restrict__ ccnt) {
    const int i = blockIdx.x * 1024 + threadIdx.x;
    hist[i] = 0u;
    if (i < 2) ccnt[i] = 0u;
}

__global__ __launch_bounds__(1024) void k_tkscan(const unsigned* __restrict__ hist,
                                                 unsigned* __restrict__ pivot) {
    __shared__ unsigned ls[1024];
    __shared__ unsigned s_owner, s_carry;
    const int b = blockIdx.x, t = threadIdx.x;
    const unsigned* h = hist + (size_t)b * TKBINS;
    if (t == 0) { s_owner = 0u; s_carry = 0u; pivot[b] = 0u; }
    unsigned s = 0;
    const int base = t * 256;
    for (int i = 0; i < 256; ++i) s += h[base + i];
    ls[t] = s;
    __syncthreads();
    for (int off = 1; off < 1024; off <<= 1) {
        const unsigned add = (t + off < 1024) ? ls[t + off] : 0u;
        __syncthreads();
        ls[t] += add;
        __syncthreads();
    }
    {
        const unsigned here = ls[t];
        const unsigned above = (t + 1 < 1024) ? ls[t + 1] : 0u;
        if (here >= 200u && above < 200u) { s_owner = (unsigned)t; s_carry = above; }
    }
    __syncthreads();
    const int owner = (int)s_owner;
    const unsigned carry = s_carry;
    __syncthreads();
    ls[t] = (t < 256) ? h[owner * 256 + t] : 0u;
    __syncthreads();
    for (int off = 1; off < 1024; off <<= 1) {
        const unsigned add = (t + off < 1024) ? ls[t + off] : 0u;
        __syncthreads();
        ls[t] += add;
        __syncthreads();
    }
    if (t < 256) {
        const unsigned here = carry + ls[t];
        const unsigned above = carry + ((t + 1 < 1024) ? ls[t + 1] : 0u);
        if (here >= 200u && above < 200u)
            pivot[b] = (unsigned)(owner * 256 + t) << 14;
    }
}

__global__ __launch_bounds__(1024) void k_tkcollect(const float* __restrict__ hm_msk,
    const unsigned* __restrict__ pivot, unsigned long long* __restrict__ cand,
    unsigned* __restrict__ ccnt) {
    const int b = blockIdx.y;
    const int i = blockIdx.x * 1024 + threadIdx.x;
    if (i >= NTOT) return;
    const unsigned key = __float_as_uint(hm_msk[(size_t)b * NTOT + i]);
    if (key >= pivot[b] && key != 0u) {
        const unsigned pos = atomicAdd(&ccnt[b], 1u);
        if (pos < 4096u)
            cand[(size_t)b * 4096 + pos] = (((unsigned long long)(~key)) << 32) | (unsigned)i;
    }
}

__global__ __launch_bounds__(1024) void k_tksort(const unsigned long long* __restrict__ cand,
    const unsigned* __restrict__ ccnt, int* __restrict__ top_idx) {
    __shared__ unsigned long long sb[4096];
    const int b = blockIdx.x, t = threadIdx.x;
    const unsigned cnt = ccnt[b] < 4096u ? ccnt[b] : 4096u;
    if (cnt <= 1024u) {
        sb[t] = ((unsigned)t < cnt) ? cand[(size_t)b * 4096 + t] : 0xFFFFFFFFFFFFFFFFull;
        __syncthreads();
        for (int k = 2; k <= 1024; k <<= 1) {
            for (int j = k >> 1; j > 0; j >>= 1) {
                const int ixj = t ^ j;
                if (ixj > t) {
                    const unsigned long long a = sb[t], c = sb[ixj];
                    const bool up = ((t & k) == 0);
                    if ((a > c) == up) { sb[t] = c; sb[ixj] = a; }
                }
                __syncthreads();
            }
        }
    } else {
        for (int e = t; e < 4096; e += 1024)
            sb[e] = ((unsigned)e < cnt) ? cand[(size_t)b * 4096 + e] : 0xFFFFFFFFFFFFFFFFull;
        __syncthreads();
        for (int k = 2; k <= 4096; k <<= 1) {
            for (int j = k >> 1; j > 0; j >>= 1) {
                for (int e = t; e < 4096; e += 1024) {
                    const int ixj = e ^ j;
                    if (ixj > e) {
                        const unsigned long long a = sb[e], c = sb[ixj];
                        const bool up = ((e & k) == 0);
                        if ((a > c) == up) { sb[e] = c; sb[ixj] = a; }
                    }
                }
                __syncthreads();
            }
        }
    }
    if (t < 200) top_idx[b * 200 + t] = (int)(sb[t] & 0xFFFFFFFFull) % HWN;
}

// ------ kpe for all BEV positions (16 pos/block, stored transposed) -----------
__global__ __launch_bounds__(128) void k_kpe(const float* __restrict__ w1,
    const float* __restrict__ b1, const float* __restrict__ w2,
    const float* __restrict__ b2, float* __restrict__ kpeT)
{
    __shared__ float pe[16][258];
    __shared__ float hid[16][130];
    const int tid = threadIdx.x;
    const int pos0 = blockIdx.x * 16;
    const int half = tid >> 6, m = tid & 63;
    const float dimt = 1.f + (float)m * 0.015625f;
#pragma unroll
    for (int p = 0; p < 16; ++p) {
        const int pos = pos0 + p;
        const int i = pos / WW, j = pos % WW;
        const float coord = (half == 0) ? ((float)j + 0.5f) * (1.f / 180.f)
                                        : ((float)i + 0.5f) * (1.f / 180.f);
        const float arg = (coord * 6.2831855f) / dimt;
        pe[p][half * 128 + 2 * m]     = sinf(arg);
        pe[p][half * 128 + 2 * m + 1] = cosf(arg);
    }
    __syncthreads();
    float acc[16];
#pragma unroll
    for (int p = 0; p < 16; ++p) acc[p] = b1[tid];
    for (int k = 0; k < 256; ++k) {
        const float w = w1[k * 128 + tid];
#pragma unroll
        for (int p = 0; p < 16; ++p) acc[p] += pe[p][k] * w;
    }
#pragma unroll
    for (int p = 0; p < 16; ++p) hid[p][tid] = fmaxf(acc[p], 0.f);
    __syncthreads();
#pragma unroll
    for (int p = 0; p < 16; ++p) acc[p] = b2[tid];
    for (int k = 0; k < 128; ++k) {
        const float w = w2[k * 128 + tid];
#pragma unroll
        for (int p = 0; p < 16; ++p) acc[p] += hid[p][k] * w;
    }
#pragma unroll
    for (int p = 0; p < 16; ++p) kpeT[(size_t)tid * HWN + pos0 + p] = acc[p];
}

// ---------------- gather q0/qpe/q_hm ------------------------------------------
__global__ __launch_bounds__(128) void k_gather(const float* __restrict__ feat,
    const float* __restrict__ kpeT, const float* __restrict__ hm_msk,
    const int* __restrict__ top_idx, float* __restrict__ q0,
    float* __restrict__ qpe, float* __restrict__ qhm)
{
    const int p = blockIdx.x, b = blockIdx.y, c = threadIdx.x;
    const int idx = top_idx[b * 200 + p];
    q0[((size_t)b * 200 + p) * 128 + c]  = feat[((size_t)b * 128 + c) * HWN + idx];
    qpe[((size_t)b * 200 + p) * 128 + c] = kpeT[(size_t)c * HWN + idx];
    if (c < 10)
        qhm[((size_t)b * 10 + c) * 200 + p] = hm_msk[((size_t)b * 10 + c) * HWN + idx];
}

// ---------------- self-attn qkv projection ------------------------------------
__global__ __launch_bounds__(128) void k_proj_self(const float* __restrict__ q0,
    const float* __restrict__ qpe, const float* __restrict__ w,
    const float* __restrict__ bias, float* __restrict__ qh,
    float* __restrict__ kh, float* __restrict__ vh)
{
    __shared__ float in0[128], in1[128];
    const int p = blockIdx.x, b = blockIdx.y, c = threadIdx.x;
    const size_t base = ((size_t)b * 200 + p) * 128;
    const float a = q0[base + c], pe = qpe[base + c];
    in0[c] = a + pe; in1[c] = a;
    __syncthreads();
    float aq = bias[c], ak = bias[128 + c], av = bias[256 + c];
    for (int k = 0; k < 128; ++k) {
        const float i0 = in0[k];
        aq += i0 * w[k * 128 + c];
        ak += i0 * w[16384 + k * 128 + c];
        av += in1[k] * w[32768 + k * 128 + c];
    }
    qh[base + c] = aq; kh[base + c] = ak; vh[base + c] = av;
}

// ---------------- self-attention (200 keys) -----------------------------------
__global__ __launch_bounds__(256) void k_attn_self(const float* __restrict__ qh,
    const float* __restrict__ kh, const float* __restrict__ vh, float* __restrict__ o)
{
    __shared__ float ks[200][16], vs[200][16];
    const int h = blockIdx.x, b = blockIdx.y, tid = threadIdx.x;
    for (int s = tid; s < 3200; s += 256) {
        const int n = s >> 4, d = s & 15;
        ks[n][d] = kh[((size_t)b * 200 + n) * 128 + h * 16 + d];
        vs[n][d] = vh[((size_t)b * 200 + n) * 128 + h * 16 + d];
    }
    __syncthreads();
    if (tid < 200) {
        float q[16];
#pragma unroll
        for (int d = 0; d < 16; ++d)
            q[d] = qh[((size_t)b * 200 + tid) * 128 + h * 16 + d] * 0.25f;
        float mmax = -1e30f, lsum = 0.f, acc[16];
#pragma unroll
        for (int d = 0; d < 16; ++d) acc[d] = 0.f;
        for (int j = 0; j < 200; ++j) {
            float s = 0.f;
#pragma unroll
            for (int d = 0; d < 16; ++d) s += q[d] * ks[j][d];
            const float mn = fmaxf(mmax, s);
            const float corr = __expf(mmax - mn);
            const float pv = __expf(s - mn);
            lsum = lsum * corr + pv;
#pragma unroll
            for (int d = 0; d < 16; ++d) acc[d] = acc[d] * corr + pv * vs[j][d];
            mmax = mn;
        }
#pragma unroll
        for (int d = 0; d < 16; ++d)
            o[((size_t)b * 200 + tid) * 128 + h * 16 + d] = acc[d] / lsum;
    }
}

// ---- out-projection + residual + LN (+ optional fused cross-Q projection) ----
template<int FUSEQ>
__global__ __launch_bounds__(128) void k_proj_ln(const float* __restrict__ src,
    const float* __restrict__ W, const float* __restrict__ bW,
    const float* __restrict__ resid, const float* __restrict__ g,
    const float* __restrict__ lb, float* __restrict__ out,
    const float* __restrict__ qpe, const float* __restrict__ wq,
    const float* __restrict__ bq, float* __restrict__ qout)
{
    __shared__ float sIn[128];
    __shared__ float rbuf[4];
    __shared__ float lnrow[128];
    const int p = blockIdx.x, b = blockIdx.y, c = threadIdx.x;
    const size_t base = ((size_t)b * 200 + p) * 128;
    sIn[c] = src[base + c];
    __syncthreads();
    float v = bW[c] + resid[base + c];
    for (int k = 0; k < 128; ++k) v += sIn[k] * W[k * 128 + c];
    float s = v;
#pragma unroll
    for (int off = 32; off >= 1; off >>= 1) s += __shfl_xor(s, off);
    if ((c & 63) == 0) rbuf[c >> 6] = s;
    __syncthreads();
    const float mean = (rbuf[0] + rbuf[1]) * (1.f / 128.f);
    const float dv = v - mean;
    float s2 = dv * dv;
#pragma unroll
    for (int off = 32; off >= 1; off >>= 1) s2 += __shfl_xor(s2, off);
    if ((c & 63) == 0) rbuf[2 + (c >> 6)] = s2;
    __syncthreads();
    const float var = (rbuf[2] + rbuf[3]) * (1.f / 128.f);
    const float ln = g[c] * dv / sqrtf(var + 1e-5f) + lb[c];
    out[base + c] = ln;
    if (FUSEQ) {
        lnrow[c] = ln + qpe[base + c];
        __syncthreads();
        float a = bq[c];
        for (int k = 0; k < 128; ++k) a += lnrow[k] * wq[k * 128 + c];
        qout[base + c] = a;
    }
}

// ------ cross K/V projection over HW -> fp16-split K [bh][n][2][16],
//        V transposed [bh][2][16][HWN] ----------------------------------------
__global__ __launch_bounds__(256) void k_kv_cross(const float* __restrict__ feat,
    const float* __restrict__ kpeT, const float* __restrict__ w,
    const float* __restrict__ bias, _Float16* __restrict__ khs,
    _Float16* __restrict__ vTs)
{
    __shared__ float as[32][68];
    __shared__ float wk[32][128], wv[32][128];
    const int tid = threadIdx.x, n0 = blockIdx.x * 64, b = blockIdx.y;
    const int cg = tid & 31, ng = tid >> 5;
    float ak[4][8], av[4][8];
#pragma unroll
    for (int i = 0; i < 4; ++i)
#pragma unroll
        for (int j = 0; j < 8; ++j) { ak[i][j] = 0.f; av[i][j] = 0.f; }
    for (int kc = 0; kc < 128; kc += 32) {
        for (int s = tid; s < 2048; s += 256) {
            const int k = s >> 6, n = s & 63;
            float fv = 0.f;
            if (n0 + n < HWN)
                fv = feat[((size_t)b * 128 + kc + k) * HWN + n0 + n]
                   + kpeT[(size_t)(kc + k) * HWN + n0 + n];
            as[k][n] = fv;
        }
        for (int s = tid; s < 4096; s += 256) {
            const int k = s >> 7, c = s & 127;
            wk[k][c] = w[(128 + kc + k) * 128 + c];
            wv[k][c] = w[(256 + kc + k) * 128 + c];
        }
        __syncthreads();
#pragma unroll
        for (int k = 0; k < 32; ++k) {
            const float4 x0 = *(const float4*)&as[k][ng * 8];
            const float4 x1 = *(const float4*)&as[k][ng * 8 + 4];
            const float4 wk4 = *(const float4*)&wk[k][cg * 4];
            const float4 wv4 = *(const float4*)&wv[k][cg * 4];
            float xv[8] = {x0.x, x0.y, x0.z, x0.w, x1.x, x1.y, x1.z, x1.w};
#pragma unroll
            for (int j = 0; j < 8; ++j) {
                ak[0][j] += wk4.x * xv[j]; ak[1][j] += wk4.y * xv[j];
                ak[2][j] += wk4.z * xv[j]; ak[3][j] += wk4.w * xv[j];
                av[0][j] += wv4.x * xv[j]; av[1][j] += wv4.y * xv[j];
                av[2][j] += wv4.z * xv[j]; av[3][j] += wv4.w * xv[j];
            }
        }
        __syncthreads();
    }
    float bk[4], bv[4];
#pragma unroll
    for (int i = 0; i < 4; ++i) {
        bk[i] = bias[128 + cg * 4 + i];
        bv[i] = bias[256 + cg * 4 + i];
    }
    const int h = cg >> 2;            // (cg*4)/16
    const int d0 = (cg * 4) & 15;
    const int bh = b * 8 + h;
    // K: [bh][n][t2][16d] (fp16 split)
#pragma unroll
    for (int j = 0; j < 8; ++j) {
        const int n = n0 + ng * 8 + j;
        if (n < HWN) {
            half4 kh4, kl4;
#pragma unroll
            for (int i = 0; i < 4; ++i) {
                const float v = ak[i][j] + bk[i];
                const _Float16 hh = (_Float16)v;
                kh4[i] = hh;
                kl4[i] = (_Float16)((v - (float)hh) * 256.f);
            }
            _Float16* kp = khs + ((size_t)bh * HWN + n) * 32 + d0;
            *(half4*)kp = kh4;
            *(half4*)(kp + 16) = kl4;
        }
    }
    // V^T: [bh][t2][16d][HWN] (fp16 split)
    const int nb = n0 + ng * 8;
#pragma unroll
    for (int i = 0; i < 4; ++i) {
        half8 vh8, vl8;
#pragma unroll
        for (int j = 0; j < 8; ++j) {
            const float v = av[i][j] + bv[i];
            const _Float16 hh = (_Float16)v;
            vh8[j] = hh;
            vl8[j] = (_Float16)((v - (float)hh) * 256.f);
        }
        _Float16* p0 = vTs + ((size_t)(bh * 2 + 0) * 16 + d0 + i) * HWN + nb;
        _Float16* p1 = vTs + ((size_t)(bh * 2 + 1) * 16 + d0 + i) * HWN + nb;
        if (nb + 8 <= HWN) {
            *(half8*)p0 = vh8;
            *(half8*)p1 = vl8;
        } else {
#pragma unroll
            for (int j = 0; j < 8; ++j)
                if (nb + j < HWN) { p0[j] = vh8[j]; p1[j] = vl8[j]; }
        }
    }
}

// ------ MFMA flash cross-attention (swapped QK^T, swapped PV), split-K --------
// 1-wave blocks, grid (7 qtile, 16 bh, KSPLIT). fp16 two-term split on K,Q,V.
__global__ __launch_bounds__(64) void k_flash(const float* __restrict__ qh,
    const _Float16* __restrict__ khs, const _Float16* __restrict__ vTs,
    float* __restrict__ o_part, float* __restrict__ m_part, float* __restrict__ l_part)
{
    const int qt = blockIdx.x, bh = blockIdx.y, ksid = blockIdx.z;
    const int b = bh >> 3, h = bh & 7;
    const int l = threadIdx.x;
    const int l31 = l & 31, kb = l >> 5;
    const int kb4 = kb * 4;
    const int q = qt * 32 + l31;
    const float inv256 = 1.f / 256.f;

    // Q B-fragments (pre-scaled 0.25, fp16 split)
    half8 qbh, qbl;
    {
        float qv[8];
        if (q < 200) {
            const float* qp = qh + ((size_t)b * 200 + q) * 128 + h * 16 + kb * 8;
#pragma unroll
            for (int j = 0; j < 8; ++j) qv[j] = qp[j] * 0.25f;
        } else {
#pragma unroll
            for (int j = 0; j < 8; ++j) qv[j] = 0.f;
        }
#pragma unroll
        for (int j = 0; j < 8; ++j) {
            const _Float16 hh = (_Float16)qv[j];
            qbh[j] = hh;
            qbl[j] = (_Float16)((qv[j] - (float)hh) * 256.f);
        }
    }

    const int nBase = ksid * (HWN / KSPLIT), nEnd = nBase + (HWN / KSPLIT);
    float m = -1e30f, lsum = 0.f;
    f32x16 acc3 = {}, acc4 = {};
    const size_t kbase = (size_t)bh * HWN;
    const size_t vb0 = ((size_t)(bh * 2 + 0) * 16 + l31) * (size_t)HWN;
    const size_t vb1 = ((size_t)(bh * 2 + 1) * 16 + l31) * (size_t)HWN;

    for (int c0 = nBase; c0 < nEnd; c0 += 32) {
        // K A-frags: row=l31 (k-in-tile), kslot d = kb*8+j
        int kcol = c0 + l31; if (kcol >= HWN) kcol = HWN - 1;
        const _Float16* kp = khs + (kbase + kcol) * 32 + kb * 8;
        const half8 kah = *(const half8*)kp;
        const half8 kal = *(const half8*)(kp + 16);
        f32x16 a1 = {}, a2 = {};
        a1 = MFMA16(kah, qbh, a1);
        a2 = MFMA16(kah, qbl, a2);
        a2 = MFMA16(kal, qbh, a2);
        // scores (D: col=q=l31, row=k=(r&3)+8*(r>>2)+4*kb) + boundary mask
        float s[16];
        float cm = -1e30f;
#pragma unroll
        for (int r = 0; r < 16; ++r) {
            const int kk = (r & 3) + 8 * (r >> 2) + kb4;
            float v = a1[r] + a2[r] * inv256;
            v = (c0 + kk < nEnd) ? v : -1e30f;
            s[r] = v;
            cm = fmaxf(cm, v);
        }
        cm = fmaxf(cm, __shfl_xor(cm, 32));
        const float mn = fmaxf(m, cm);
        const float corr = __expf(m - mn);
        lsum *= corr;
#pragma unroll
        for (int r = 0; r < 16; ++r) { acc3[r] *= corr; acc4[r] *= corr; }
        float p[16];
#pragma unroll
        for (int r = 0; r < 16; ++r) { p[r] = __expf(s[r] - mn); lsum += p[r]; }
        m = mn;
        // pack P to fp16, exchange across kb-half lanes, build P^T B-frags
        const u32 o01 = pkh(p[0], p[1]),  o23 = pkh(p[2], p[3]);
        const u32 o45 = pkh(p[4], p[5]),  o67 = pkh(p[6], p[7]);
        const u32 o89 = pkh(p[8], p[9]),  oAB = pkh(p[10], p[11]);
        const u32 oCD = pkh(p[12], p[13]), oEF = pkh(p[14], p[15]);
        const u32 x01 = __shfl_xor(o01, 32), x23 = __shfl_xor(o23, 32);
        const u32 x45 = __shfl_xor(o45, 32), x67 = __shfl_xor(o67, 32);
        const u32 x89 = __shfl_xor(o89, 32), xAB = __shfl_xor(oAB, 32);
        const u32 xCD = __shfl_xor(oCD, 32), xEF = __shfl_xor(oEF, 32);
        const half8 pb0 = (kb == 0) ? mkh8(o01, o23, x01, x23) : mkh8(x45, x67, o45, o67);
        const half8 pb1 = (kb == 0) ? mkh8(o89, oAB, x89, xAB) : mkh8(xCD, xEF, oCD, oEF);
        // V^T A-frags: row=l31=d (valid <16), kslot = khalf*16 + kb*8 + j
        half8 vh0 = {}, vl0 = {}, vh1 = {}, vl1 = {};
        if (l31 < 16) {
            const int cA = c0 + kb * 8;
            const int cB = c0 + 16 + kb * 8;
            if (cB + 8 <= HWN) {
                vh0 = *(const half8*)(vTs + vb0 + cA);
                vh1 = *(const half8*)(vTs + vb0 + cB);
                vl0 = *(const half8*)(vTs + vb1 + cA);
                vl1 = *(const half8*)(vTs + vb1 + cB);
            } else {
#pragma unroll
                for (int j = 0; j < 8; ++j) {
                    if (cA + j < HWN) { vh0[j] = vTs[vb0 + cA + j]; vl0[j] = vTs[vb1 + cA + j]; }
                    if (cB + j < HWN) { vh1[j] = vTs[vb0 + cB + j]; vl1[j] = vTs[vb1 + cB + j]; }
                }
            }
        }
        acc3 = MFMA16(vh0, pb0, acc3);
        acc3 = MFMA16(vh1, pb1, acc3);
        acc4 = MFMA16(vl0, pb0, acc4);
        acc4 = MFMA16(vl1, pb1, acc4);
    }

    const float lt = lsum + __shfl_xor(lsum, 32);
    if (q < 200) {
        const size_t pbase = ((size_t)bh * KSPLIT + ksid) * 200 + q;
        if (kb == 0) { m_part[pbase] = m; l_part[pbase] = lt; }
#pragma unroll
        for (int r = 0; r < 8; ++r) {
            const int d = (r & 3) + 8 * (r >> 2) + kb4;
            o_part[pbase * 16 + d] = acc3[r] + acc4[r] * inv256;
        }
    }
}

// ---------------- merge flash splits ------------------------------------------
__global__ __launch_bounds__(64) void k_merge(const float* __restrict__ o_part,
    const float* __restrict__ m_part, const float* __restrict__ l_part,
    float* __restrict__ o_c)
{
    const int row = blockIdx.x, bh = blockIdx.y;
    const int b = bh >> 3, h = bh & 7;
    const int lane = threadIdx.x;
    float M = -1e30f;
#pragma unroll
    for (int k = 0; k < KSPLIT; ++k)
        M = fmaxf(M, m_part[((size_t)bh * KSPLIT + k) * 200 + row]);
    float L = 0.f;
#pragma unroll
    for (int k = 0; k < KSPLIT; ++k)
        L += l_part[((size_t)bh * KSPLIT + k) * 200 + row]
           * __expf(m_part[((size_t)bh * KSPLIT + k) * 200 + row] - M);
    if (lane < 16) {
        float o = 0.f;
#pragma unroll
        for (int k = 0; k < KSPLIT; ++k)
            o += o_part[(((size_t)bh * KSPLIT + k) * 200 + row) * 16 + lane]
               * __expf(m_part[((size_t)bh * KSPLIT + k) * 200 + row] - M);
        o_c[((size_t)b * 200 + row) * 128 + h * 16 + lane] = o / L;
    }
}

// ---------------- FFN + residual + LN3 ----------------------------------------
__global__ __launch_bounds__(256) void k_ffn_ln(const float* __restrict__ x,
    const float* __restrict__ w1, const float* __restrict__ b1,
    const float* __restrict__ w2, const float* __restrict__ b2,
    const float* __restrict__ g, const float* __restrict__ lb, float* __restrict__ out)
{
    __shared__ float xr[128];
    __shared__ float hs[256];
    __shared__ float rbuf[8];
    const int p = blockIdx.x, b = blockIdx.y, t = threadIdx.x;
    const size_t base = ((size_t)b * 200 + p) * 128;
    if (t < 128) xr[t] = x[base + t];
    __syncthreads();
    float hv = b1[t];
    for (int k = 0; k < 128; ++k) hv += xr[k] * w1[k * 256 + t];
    hs[t] = fmaxf(hv, 0.f);
    __syncthreads();
    float v = 0.f;
    if (t < 128) {
        v = b2[t] + xr[t];
        for (int k = 0; k < 256; ++k) v += hs[k] * w2[k * 128 + t];
    }
    float s = (t < 128) ? v : 0.f;
#pragma unroll
    for (int off = 32; off >= 1; off >>= 1) s += __shfl_xor(s, off);
    if ((t & 63) == 0) rbuf[t >> 6] = s;
    __syncthreads();
    const float mean = (rbuf[0] + rbuf[1] + rbuf[2] + rbuf[3]) * (1.f / 128.f);
    const float dv = v - mean;
    float s2 = (t < 128) ? dv * dv : 0.f;
#pragma unroll
    for (int off = 32; off >= 1; off >>= 1) s2 += __shfl_xor(s2, off);
    if ((t & 63) == 0) rbuf[4 + (t >> 6)] = s2;
    __syncthreads();
    const float var = (rbuf[4] + rbuf[5] + rbuf[6] + rbuf[7]) * (1.f / 128.f);
    if (t < 128) out[base + t] = g[t] * dv / sqrtf(var + 1e-5f) + lb[t];
}

// ---------------- separate heads: conv1 + BN + ReLU ---------------------------
__global__ __launch_bounds__(256) void k_head_h(const float* __restrict__ q3,
    const float* __restrict__ w1, const float* __restrict__ b1,
    const float* __restrict__ g, const float* __restrict__ beta,
    float* __restrict__ h_all)
{
    __shared__ float qw[128][32];
    const int pt = blockIdx.x, ih = blockIdx.y, b = blockIdx.z;
    const int tid = threadIdx.x;
    for (int s = tid; s < 4096; s += 256) {
        const int c = s & 127, wg = s >> 7;
        const int pg = pt * 24 - 1 + wg;
        qw[c][wg] = ((unsigned)pg < 200u) ? q3[((size_t)b * 200 + pg) * 128 + c] : 0.f;
    }
    __syncthreads();
    const int c = tid & 127, half = tid >> 7;
    float acc[12];
#pragma unroll
    for (int pp = 0; pp < 12; ++pp) acc[pp] = 0.f;
    const float* wbase = w1 + ((size_t)ih * 128 + c) * 384;
    for (int cin = 0; cin < 128; ++cin) {
        const float4* qp = (const float4*)&qw[cin][half * 12];
        const float4 a0 = qp[0], a1 = qp[1], a2 = qp[2], a3 = qp[3];
        float xr[16] = {a0.x, a0.y, a0.z, a0.w, a1.x, a1.y, a1.z, a1.w,
                        a2.x, a2.y, a2.z, a2.w, a3.x, a3.y, a3.z, a3.w};
        const float w0 = wbase[cin * 3], w1v = wbase[cin * 3 + 1], w2v = wbase[cin * 3 + 2];
#pragma unroll
        for (int pp = 0; pp < 12; ++pp)
            acc[pp] += xr[pp] * w0 + xr[pp + 1] * w1v + xr[pp + 2] * w2v;
    }
    const float bs = b1[ih * 128 + c], gg = g[ih * 128 + c], bt = beta[ih * 128 + c];
#pragma unroll
    for (int pp = 0; pp < 12; ++pp) {
        const int p = pt * 24 + half * 12 + pp;
        if (p < 200)
            h_all[(((size_t)b * 6 + ih) * 128 + c) * 200 + p] =
                fmaxf(gg * (acc[pp] + bs) + bt, 0.f);
    }
}

// ---------------- separate heads: conv2 + hm-score fusion ---------------------
__global__ void k_head_out(const float* __restrict__ h_all, const float* __restrict__ w2,
    const float* __restrict__ b2, const float* __restrict__ qhm, float* __restrict__ out)
{
    const int gid = blockIdx.x * 256 + threadIdx.x;
    if (gid >= 8000) return;
    const int p = gid % 200, rem = gid / 200, row = rem % 20, b = rem / 20;
    int i, oo;
    if (row < 2)       { i = 0; oo = row; }
    else if (row < 3)  { i = 1; oo = row - 2; }
    else if (row < 6)  { i = 2; oo = row - 3; }
    else if (row < 8)  { i = 3; oo = row - 6; }
    else if (row < 10) { i = 4; oo = row - 8; }
    else               { i = 5; oo = row - 10; }
    const float* hb = h_all + (((size_t)b * 6 + i) * 128) * 200;
    const float* wb = w2 + ((size_t)i * 10 + oo) * 384;
    float acc = b2[i * 10 + oo];
    for (int c = 0; c < 128; ++c) {
        const float* hr = hb + (size_t)c * 200 + p;
        const float x0 = (p > 0) ? hr[-1] : 0.f;
        const float x1 = hr[0];
        const float x2 = (p < 199) ? hr[1] : 0.f;
        acc += x0 * wb[c * 3] + x1 * wb[c * 3 + 1] + x2 * wb[c * 3 + 2];
    }
    if (i == 5) acc += qhm[((size_t)b * 10 + oo) * 200 + p];
    out[((size_t)b * 20 + row) * 200 + p] = acc;
}

// ---------------- launcher ----------------------------------------------------
extern "C" void kernel_launch(void* const* d_in, const int* in_sizes, int n_in,
                              void* d_out, int out_size, void* d_ws, size_t ws_size,
                              hipStream_t stream) {
    (void)in_sizes; (void)n_in; (void)out_size; (void)ws_size;
    const float* x        = (const float*)d_in[0];
    const float* w_shared = (const float*)d_in[1];
    const float* b_shared = (const float*)d_in[2];
    const float* w_hm1    = (const float*)d_in[3];
    const float* b_hm1    = (const float*)d_in[4];
    const float* g_hm1    = (const float*)d_in[5];
    const float* beta_hm1 = (const float*)d_in[6];
    const float* w_hm2    = (const float*)d_in[7];
    const float* b_hm2    = (const float*)d_in[8];
    const float* w_be1    = (const float*)d_in[15];
    const float* b_be1    = (const float*)d_in[16];
    const float* w_be2    = (const float*)d_in[17];
    const float* b_be2    = (const float*)d_in[18];
    const float* w_attn_s = (const float*)d_in[19];
    const float* b_attn_s = (const float*)d_in[20];
    const float* w_out_s  = (const float*)d_in[21];
    const float* b_out_s  = (const float*)d_in[22];
    const float* w_attn_c = (const float*)d_in[23];
    const float* b_attn_c = (const float*)d_in[24];
    const float* w_out_c  = (const float*)d_in[25];
    const float* b_out_c  = (const float*)d_in[26];
    const float* ln1_g    = (const float*)d_in[27];
    const float* ln1_b    = (const float*)d_in[28];
    const float* ln2_g    = (const float*)d_in[29];
    const float* ln2_b    = (const float*)d_in[30];
    const float* ln3_g    = (const float*)d_in[31];
    const float* ln3_b    = (const float*)d_in[32];
    const float* w_ff1    = (const float*)d_in[33];
    const float* b_ff1    = (const float*)d_in[34];
    const float* w_ff2    = (const float*)d_in[35];
    const float* b_ff2    = (const float*)d_in[36];
    const float* w_head1  = (const float*)d_in[37];
    const float* b_head1  = (const float*)d_in[38];
    const float* g_head1  = (const float*)d_in[39];
    const float* bt_head1 = (const float*)d_in[40];
    const float* w_head2  = (const float*)d_in[41];
    const float* b_head2  = (const float*)d_in[42];

    char* ws = (char*)d_ws;
    size_t off = 0;
    auto alloc = [&](size_t bytes) { size_t o = off; off += (bytes + 255) & ~(size_t)255; return o; };
    _Float16* wimg_s  = (_Float16*)(ws + alloc((size_t)12*9*16384));
    _Float16* wimg_h1 = (_Float16*)(ws + alloc((size_t)4*9*16384));
    _Float16* wimg_hm = (_Float16*)(ws + alloc((size_t)4*9*2048*2));
    char*     xs1reg  = (ws + alloc((size_t)2*180*12*2*180*32*2));   // 99.5 MB, dies after conv1
    _Float16* xs1     = (_Float16*)xs1reg;
    _Float16* xs2     = (_Float16*)(ws + alloc((size_t)2*180*4*2*180*32*2));
    float* feat   = (float*)(ws + alloc((size_t)2*128*HWN*4));
    _Float16* khs = (_Float16*)(ws + alloc((size_t)16*HWN*32*2));    // K fp16 split
    float* kpeT   = (float*)(ws + alloc((size_t)128*HWN*4));
    int*   topidx = (int*)  (ws + alloc((size_t)2*200*4));
    unsigned* hist  = (unsigned*)(ws + alloc((size_t)2*TKBINS*4));   // 2 MB
    unsigned* pivot = (unsigned*)(ws + alloc((size_t)2*4));
    unsigned long long* cand = (unsigned long long*)(ws + alloc((size_t)2*4096*8));
    unsigned* ccnt  = (unsigned*)(ws + alloc((size_t)2*4));
    float* q0     = (float*)(ws + alloc((size_t)2*200*128*4));
    float* qpe    = (float*)(ws + alloc((size_t)2*200*128*4));
    float* q_hm   = (float*)(ws + alloc((size_t)2*10*200*4));
    float* qh_s   = (float*)(ws + alloc((size_t)2*200*128*4));
    float* kh_s   = (float*)(ws + alloc((size_t)2*200*128*4));
    float* vh_s   = (float*)(ws + alloc((size_t)2*200*128*4));
    float* o_s    = (float*)(ws + alloc((size_t)2*200*128*4));
    float* q1n    = (float*)(ws + alloc((size_t)2*200*128*4));
    float* qh_c   = (float*)(ws + alloc((size_t)2*200*128*4));
    float* o_c    = (float*)(ws + alloc((size_t)2*200*128*4));
    float* q2n    = (float*)(ws + alloc((size_t)2*200*128*4));
    float* q3     = (float*)(ws + alloc((size_t)2*200*128*4));
    float* h_all  = (float*)(ws + alloc((size_t)2*6*128*200*4));

    // buffers aliased into xs1's region (first written after conv1 consumed xs1)
    size_t xo = 0;
    auto xalloc = [&](size_t bytes) { size_t o = xo; xo += (bytes + 255) & ~(size_t)255; return o; };
    _Float16* vTs = (_Float16*)(xs1reg + xalloc((size_t)16*2*16*HWN*2));  // V^T fp16 split
    float* hm_raw = (float*)(xs1reg + xalloc((size_t)2*10*HWN*4));
    float* hm_msk = (float*)(xs1reg + xalloc((size_t)2*10*HWN*4));
    float* o_part = (float*)(xs1reg + xalloc((size_t)16*KSPLIT*200*16*4));
    float* m_part = (float*)(xs1reg + xalloc((size_t)16*KSPLIT*200*4));
    float* l_part = (float*)(xs1reg + xalloc((size_t)16*KSPLIT*200*4));
    _Float16* h1s = (_Float16*)(xs1reg + xalloc((size_t)2*180*4*2*180*32*2)); // 33.2 MB

    k_tkzero<<<(2*TKBINS)/1024, 1024, 0, stream>>>(hist, ccnt);
    k_wsplit<<<(12*9*8192 + 255)/256, 256, 0, stream>>>(w_shared, wimg_s, CINN);
    k_wsplit<<<(4*9*8192 + 255)/256, 256, 0, stream>>>(w_hm1, wimg_h1, 128);
    k_wsplit_hm<<<(4*9*2048 + 255)/256, 256, 0, stream>>>(w_hm2, wimg_hm);
    k_xsplit<<<dim3(12, 180, 2), 256, 0, stream>>>(x, xs1, CINN, 12);
    k_kpe<<<HWN/16, 128, 0, stream>>>(w_be1, b_be1, w_be2, b_be2, kpeT);
    k_conv<12, 0, 1, 1><<<dim3(3, 90, 4), 256, 0, stream>>>(xs1, wimg_s, b_shared, nullptr, nullptr, feat, xs2);
    k_conv<4, 1, 0, 1><<<dim3(3, 90, 4), 256, 0, stream>>>(xs2, wimg_h1, b_hm1, g_hm1, beta_hm1, nullptr, h1s);
    k_convhm2m<4><<<dim3(3, 90, 2), 256, 0, stream>>>(h1s, wimg_hm, b_hm2, hm_raw);
    k_nms<<<(2*10*HWN + 255)/256, 256, 0, stream>>>(hm_raw, hm_msk, hist);
    k_tkscan<<<2, 1024, 0, stream>>>(hist, pivot);
    k_tkcollect<<<dim3(317, 2), 1024, 0, stream>>>(hm_msk, pivot, cand, ccnt);
    k_tksort<<<2, 1024, 0, stream>>>(cand, ccnt, topidx);
    k_gather<<<dim3(200, 2), 128, 0, stream>>>(feat, kpeT, hm_msk, topidx, q0, qpe, q_hm);
    k_proj_self<<<dim3(200, 2), 128, 0, stream>>>(q0, qpe, w_attn_s, b_attn_s, qh_s, kh_s, vh_s);
    k_attn_self<<<dim3(8, 2), 256, 0, stream>>>(qh_s, kh_s, vh_s, o_s);
    k_proj_ln<1><<<dim3(200, 2), 128, 0, stream>>>(o_s, w_out_s, b_out_s, q0, ln1_g, ln1_b, q1n,
                                                   qpe, w_attn_c, b_attn_c, qh_c);
    k_kv_cross<<<dim3(507, 2), 256, 0, stream>>>(feat, kpeT, w_attn_c, b_attn_c, khs, vTs);
    k_flash<<<dim3(7, 16, KSPLIT), 64, 0, stream>>>(qh_c, khs, vTs, o_part, m_part, l_part);
    k_merge<<<dim3(200, 16), 64, 0, stream>>>(o_part, m_part, l_part, o_c);
    k_proj_ln<0><<<dim3(200, 2), 128, 0, stream>>>(o_c, w_out_c, b_out_c, q1n, ln2_g, ln2_b, q2n,
                                                   nullptr, nullptr, nullptr, nullptr);
    k_ffn_ln<<<dim3(200, 2), 256, 0, stream>>>(q2n, w_ff1, b_ff1, w_ff2, b_ff2, ln3_g, ln3_b, q3);
    k_head_h<<<dim3(9, 6, 2), 256, 0, stream>>>(q3, w_head1, b_head1, g_head1, bt_head1, h_all);
    k_head_out<<<32, 256, 0, stream>>>(h_all, w_head2, b_head2, q_hm, (float*)d_out);
}